// Round 3
// baseline (631.001 us; speedup 1.0000x reference)
//
#include <hip/hip_runtime.h>
#include <math.h>

#define TOK 25

// ---------------- patchify: x[1,256,20,20] -> P[25][4096] (idx = c*16+kh*4+kw)
__global__ __launch_bounds__(256) void k_patchify(const float* __restrict__ x,
                                                  float* __restrict__ P) {
  int idx = blockIdx.x * 256 + threadIdx.x;  // 0..102399
  int n = idx >> 12;
  int rem = idx & 4095;
  int c = rem >> 4;
  int kh = (rem >> 2) & 3;
  int kw = rem & 3;
  int py = n / 5, px = n - py * 5;
  P[idx] = x[c * 400 + (py * 4 + kh) * 20 + (px * 4 + kw)];
}

#define COMP8(W8, KKOFF)                                                      \
  _Pragma("unroll") for (int r = 0; r < TOK; ++r) {                           \
    const float4 a =                                                          \
        *reinterpret_cast<const float4*>(&As[r * KCV + (KKOFF)]);             \
    const float4 a2 =                                                         \
        *reinterpret_cast<const float4*>(&As[r * KCV + (KKOFF) + 4]);         \
    acc[r] = fmaf(a.x, W8[0], acc[r]);                                        \
    acc[r] = fmaf(a.y, W8[1], acc[r]);                                        \
    acc[r] = fmaf(a.z, W8[2], acc[r]);                                        \
    acc[r] = fmaf(a.w, W8[3], acc[r]);                                        \
    acc[r] = fmaf(a2.x, W8[4], acc[r]);                                       \
    acc[r] = fmaf(a2.y, W8[5], acc[r]);                                       \
    acc[r] = fmaf(a2.z, W8[6], acc[r]);                                       \
    acc[r] = fmaf(a2.w, W8[7], acc[r]);                                       \
  }

#define COMP8W(WA, WB, KKOFF)                                                 \
  _Pragma("unroll") for (int r = 0; r < TOK; ++r) {                           \
    const float4 a =                                                          \
        *reinterpret_cast<const float4*>(&As[r * KCV + (KKOFF)]);             \
    const float4 a2 =                                                         \
        *reinterpret_cast<const float4*>(&As[r * KCV + (KKOFF) + 4]);         \
    acc[r] = fmaf(a.x, WA.x, acc[r]);                                         \
    acc[r] = fmaf(a.y, WA.y, acc[r]);                                         \
    acc[r] = fmaf(a.z, WA.z, acc[r]);                                         \
    acc[r] = fmaf(a.w, WA.w, acc[r]);                                         \
    acc[r] = fmaf(a2.x, WB.x, acc[r]);                                        \
    acc[r] = fmaf(a2.y, WB.y, acc[r]);                                        \
    acc[r] = fmaf(a2.z, WB.z, acc[r]);                                        \
    acc[r] = fmaf(a2.w, WB.w, acc[r]);                                        \
  }

// ---------------- GEMM, W in [Nout][K] layout (conv weight). partial[S][25][Nout]
template <int KCV>
__global__ __launch_bounds__(256) void k_gemm_wt(const float* __restrict__ A,
                                                 const float* __restrict__ W,
                                                 float* __restrict__ part,
                                                 int K, int Nout) {
  __shared__ float As[TOK * KCV];
  const int s = blockIdx.y;
  const int k0 = s * KCV;
  const int o = blockIdx.x * 256 + threadIdx.x;
  for (int i = threadIdx.x; i < TOK * (KCV / 4); i += 256) {
    int r = i / (KCV / 4);
    int k4 = i - r * (KCV / 4);
    reinterpret_cast<float4*>(As)[i] =
        reinterpret_cast<const float4*>(A + (long)r * K + k0)[k4];
  }
  __syncthreads();
  float acc[TOK];
#pragma unroll
  for (int r = 0; r < TOK; ++r) acc[r] = 0.f;
  const float* wp = W + (long)o * K + k0;
  float4 wa0 = *reinterpret_cast<const float4*>(wp + 0);
  float4 wb0 = *reinterpret_cast<const float4*>(wp + 4);
  float4 wa1 = *reinterpret_cast<const float4*>(wp + 8);
  float4 wb1 = *reinterpret_cast<const float4*>(wp + 12);
  for (int kk = 0; kk < KCV; kk += 16) {
    COMP8W(wa0, wb0, kk);
    if (kk + 16 < KCV) {
      wa0 = *reinterpret_cast<const float4*>(wp + kk + 16);
      wb0 = *reinterpret_cast<const float4*>(wp + kk + 20);
    }
    COMP8W(wa1, wb1, kk + 8);
    if (kk + 16 < KCV) {
      wa1 = *reinterpret_cast<const float4*>(wp + kk + 24);
      wb1 = *reinterpret_cast<const float4*>(wp + kk + 28);
    }
  }
  float* pp = part + ((long)s * TOK) * Nout + o;
#pragma unroll
  for (int r = 0; r < TOK; ++r) pp[(long)r * Nout] = acc[r];
}

// ---------------- GEMM, W in [K][Nout] layout (all linear layers)
template <int KCV>
__global__ __launch_bounds__(256) void k_gemm(const float* __restrict__ A,
                                              const float* __restrict__ W,
                                              float* __restrict__ part,
                                              int K, int Nout) {
  __shared__ float As[TOK * KCV];
  const int s = blockIdx.y;
  const int k0 = s * KCV;
  const int c = blockIdx.x * 256 + threadIdx.x;
  for (int i = threadIdx.x; i < TOK * (KCV / 4); i += 256) {
    int r = i / (KCV / 4);
    int k4 = i - r * (KCV / 4);
    reinterpret_cast<float4*>(As)[i] =
        reinterpret_cast<const float4*>(A + (long)r * K + k0)[k4];
  }
  __syncthreads();
  float acc[TOK];
#pragma unroll
  for (int r = 0; r < TOK; ++r) acc[r] = 0.f;
  const long ldw = Nout;
  const float* wp = W + (long)k0 * ldw + c;
  float wA[8], wB[8];
#pragma unroll
  for (int j = 0; j < 8; ++j) wA[j] = wp[(long)j * ldw];
#pragma unroll
  for (int j = 0; j < 8; ++j) wB[j] = wp[(long)(8 + j) * ldw];
  wp += 16 * ldw;
  for (int kk = 0; kk < KCV; kk += 16) {
    COMP8(wA, kk);
    if (kk + 16 < KCV) {
#pragma unroll
      for (int j = 0; j < 8; ++j) wA[j] = wp[(long)j * ldw];
    }
    COMP8(wB, kk + 8);
    if (kk + 16 < KCV) {
#pragma unroll
      for (int j = 0; j < 8; ++j) wB[j] = wp[(long)(8 + j) * ldw];
      wp += 16 * ldw;
    }
  }
  float* pp = part + ((long)s * TOK) * Nout + c;
#pragma unroll
  for (int r = 0; r < TOK; ++r) pp[(long)r * Nout] = acc[r];
}

// ---------------- reduce partials + bias (+gelu) (+residual), float4 per thread
template <int S, int GELU, int RES>
__global__ __launch_bounds__(256) void k_reduce(const float* __restrict__ part,
                                                const float* __restrict__ bias,
                                                const float* __restrict__ res,
                                                float* __restrict__ out,
                                                int Nout) {
  long idx4 = (long)blockIdx.x * 256 + threadIdx.x;  // float4 index
  int c4 = (int)(idx4 % (Nout >> 2));
  const long stride4 = (long)TOK * (Nout >> 2);
  const float4* p4 = reinterpret_cast<const float4*>(part) + idx4;
  float4 v = {0.f, 0.f, 0.f, 0.f};
#pragma unroll 16
  for (int s = 0; s < S; ++s) {
    float4 t = p4[s * stride4];
    v.x += t.x; v.y += t.y; v.z += t.z; v.w += t.w;
  }
  float4 bb = reinterpret_cast<const float4*>(bias)[c4];
  v.x += bb.x; v.y += bb.y; v.z += bb.z; v.w += bb.w;
  if (GELU) {
    v.x = 0.5f * v.x * (1.f + erff(v.x * 0.70710678118654752f));
    v.y = 0.5f * v.y * (1.f + erff(v.y * 0.70710678118654752f));
    v.z = 0.5f * v.z * (1.f + erff(v.z * 0.70710678118654752f));
    v.w = 0.5f * v.w * (1.f + erff(v.w * 0.70710678118654752f));
  }
  if (RES) {
    float4 rr = reinterpret_cast<const float4*>(res)[idx4];
    v.x += rr.x; v.y += rr.y; v.z += rr.z; v.w += rr.w;
  }
  reinterpret_cast<float4*>(out)[idx4] = v;
}

// ---------------- fused: T = sum(part)+bias+res ; H = LayerNorm(T). one block/token
template <int S>
__global__ __launch_bounds__(256) void k_reduce_ln(
    const float* __restrict__ part, const float* __restrict__ bias,
    const float* __restrict__ res, const float* __restrict__ g,
    const float* __restrict__ b, float* __restrict__ Tout,
    float* __restrict__ h) {
  const int n = blockIdx.x;
  const int tid = threadIdx.x;
  float4 v[4];
#pragma unroll
  for (int it = 0; it < 4; ++it) v[it] = make_float4(0.f, 0.f, 0.f, 0.f);
  const float4* p4 = reinterpret_cast<const float4*>(part) + (long)n * 1024;
#pragma unroll 4
  for (int s = 0; s < S; ++s) {
    const float4* ps = p4 + (long)s * TOK * 1024;
#pragma unroll
    for (int it = 0; it < 4; ++it) {
      float4 t = ps[it * 256 + tid];
      v[it].x += t.x; v[it].y += t.y; v[it].z += t.z; v[it].w += t.w;
    }
  }
  const float4* bias4 = reinterpret_cast<const float4*>(bias);
  const float4* res4 = reinterpret_cast<const float4*>(res) + (long)n * 1024;
  float4* T4 = reinterpret_cast<float4*>(Tout) + (long)n * 1024;
  float s1 = 0.f, s2 = 0.f;
#pragma unroll
  for (int it = 0; it < 4; ++it) {
    int i = it * 256 + tid;
    float4 bb = bias4[i];
    float4 rr = res4[i];
    v[it].x += bb.x + rr.x; v[it].y += bb.y + rr.y;
    v[it].z += bb.z + rr.z; v[it].w += bb.w + rr.w;
    T4[i] = v[it];
    s1 += v[it].x + v[it].y + v[it].z + v[it].w;
    s2 += v[it].x * v[it].x + v[it].y * v[it].y + v[it].z * v[it].z +
          v[it].w * v[it].w;
  }
#pragma unroll
  for (int off = 32; off >= 1; off >>= 1) {
    s1 += __shfl_down(s1, off);
    s2 += __shfl_down(s2, off);
  }
  __shared__ float red[8];
  if ((tid & 63) == 0) {
    red[tid >> 6] = s1;
    red[4 + (tid >> 6)] = s2;
  }
  __syncthreads();
  float st = red[0] + red[1] + red[2] + red[3];
  float s2t = red[4] + red[5] + red[6] + red[7];
  float mean = st * (1.f / 4096.f);
  float var = s2t * (1.f / 4096.f) - mean * mean;
  float rstd = rsqrtf(var + 1e-5f);
  const float4* g4 = reinterpret_cast<const float4*>(g);
  const float4* b4 = reinterpret_cast<const float4*>(b);
  float4* h4 = reinterpret_cast<float4*>(h) + (long)n * 1024;
#pragma unroll
  for (int it = 0; it < 4; ++it) {
    int i = it * 256 + tid;
    float4 gg = g4[i];
    float4 bb = b4[i];
    float4 o;
    o.x = (v[it].x - mean) * rstd * gg.x + bb.x;
    o.y = (v[it].y - mean) * rstd * gg.y + bb.y;
    o.z = (v[it].z - mean) * rstd * gg.z + bb.z;
    o.w = (v[it].w - mean) * rstd * gg.w + bb.w;
    h4[i] = o;
  }
}

// ---------------- attention: QK^T + softmax/64 -> att[16][25][25]
__global__ __launch_bounds__(256) void k_attn_qk(const float* __restrict__ qkv,
                                                 float* __restrict__ att) {
  const int head = blockIdx.x;
  __shared__ float q[TOK][260];
  __shared__ float k[TOK][260];
  __shared__ float e[TOK][TOK];
  const int d = threadIdx.x;
#pragma unroll
  for (int n = 0; n < TOK; ++n) {
    const long base = (long)n * 12288 + (head * 256 + d) * 3;
    q[n][d] = qkv[base];
    k[n][d] = qkv[base + 1];
  }
  __syncthreads();
  for (int p = threadIdx.x; p < TOK * TOK; p += 256) {
    int i = p / TOK, j = p - i * TOK;
    float acc = 0.f;
#pragma unroll
    for (int kk = 0; kk < 256; kk += 4) {
      float4 a = *reinterpret_cast<const float4*>(&q[i][kk]);
      float4 bb = *reinterpret_cast<const float4*>(&k[j][kk]);
      acc = fmaf(a.x, bb.x, acc);
      acc = fmaf(a.y, bb.y, acc);
      acc = fmaf(a.z, bb.z, acc);
      acc = fmaf(a.w, bb.w, acc);
    }
    e[i][j] = acc;
  }
  __syncthreads();
  if (threadIdx.x < TOK) {
    const int i = threadIdx.x;
    float m = -1e30f;
    for (int j = 0; j < TOK; ++j) m = fmaxf(m, e[i][j]);
    float ssum = 0.f;
    float ex[TOK];
#pragma unroll
    for (int j = 0; j < TOK; ++j) {
      ex[j] = expf(e[i][j] - m);
      ssum += ex[j];
    }
    float inv = 1.f / (ssum * 64.f);  // softmax then /sqrt(4096)
#pragma unroll
    for (int j = 0; j < TOK; ++j) att[head * 625 + i * TOK + j] = ex[j] * inv;
  }
}

// ---------------- attention: att @ V -> o[25][4096]
__global__ __launch_bounds__(256) void k_attn_pv(const float* __restrict__ qkv,
                                                 const float* __restrict__ att,
                                                 float* __restrict__ o) {
  const int head = blockIdx.x;
  const int d = threadIdx.x;
  __shared__ float a[TOK * TOK];
  for (int i = threadIdx.x; i < TOK * TOK; i += 256) a[i] = att[head * 625 + i];
  __syncthreads();
  float acc[TOK];
#pragma unroll
  for (int i = 0; i < TOK; ++i) acc[i] = 0.f;
#pragma unroll
  for (int j = 0; j < TOK; ++j) {
    float vv = qkv[(long)j * 12288 + (head * 256 + d) * 3 + 2];
#pragma unroll
    for (int i = 0; i < TOK; ++i) acc[i] = fmaf(a[i * TOK + j], vv, acc[i]);
  }
#pragma unroll
  for (int i = 0; i < TOK; ++i) o[(long)i * 4096 + head * 256 + d] = acc[i];
}

extern "C" void kernel_launch(void* const* d_in, const int* in_sizes, int n_in,
                              void* d_out, int out_size, void* d_ws, size_t ws_size,
                              hipStream_t stream) {
  (void)in_sizes; (void)n_in; (void)out_size; (void)ws_size;
  const float* x      = (const float*)d_in[0];
  const float* pe_w   = (const float*)d_in[1];
  const float* pe_b   = (const float*)d_in[2];
  const float* pos    = (const float*)d_in[3];
  const float* ln_g   = (const float*)d_in[4];
  const float* ln_b   = (const float*)d_in[5];
  const float* qkv_w  = (const float*)d_in[6];
  const float* qkv_b  = (const float*)d_in[7];
  const float* proj_w = (const float*)d_in[8];
  const float* proj_b = (const float*)d_in[9];
  const float* ff1_w  = (const float*)d_in[10];
  const float* ff1_b  = (const float*)d_in[11];
  const float* ff2_w  = (const float*)d_in[12];
  const float* ff2_b  = (const float*)d_in[13];
  float* out = (float*)d_out;

  float* ws = (float*)d_ws;
  float* P    = ws;             // 102400
  float* T    = ws + 102400;    // 102400
  float* H    = ws + 204800;    // 102400
  float* QKV  = ws + 307200;    // 307200
  float* O    = ws + 614400;    // 102400
  float* G    = ws + 716800;    // 409600
  float* ATT  = ws + 1126400;   // 10000
  float* PART = ws + 1136400;   // max 9.83M floats (qkv) = 39.3 MB

  // 1. patch embedding: KC=64 -> S=64, grid 16x64
  k_patchify<<<400, 256, 0, stream>>>(x, P);
  k_gemm_wt<64><<<dim3(16, 64), 256, 0, stream>>>(P, pe_w, PART, 4096, 4096);
  k_reduce_ln<64><<<25, 256, 0, stream>>>(PART, pe_b, pos, ln_g, ln_b, T, H);

  // 2. attention branch: qkv KC=128 -> S=32, grid 48x32
  k_gemm<128><<<dim3(48, 32), 256, 0, stream>>>(H, qkv_w, PART, 4096, 12288);
  k_reduce<32, 0, 0><<<300, 256, 0, stream>>>(PART, qkv_b, nullptr, QKV, 12288);
  k_attn_qk<<<16, 256, 0, stream>>>(QKV, ATT);
  k_attn_pv<<<16, 256, 0, stream>>>(QKV, ATT, O);
  // proj KC=64 -> S=64, grid 16x64; fused reduce+residual(T)+LN
  k_gemm<64><<<dim3(16, 64), 256, 0, stream>>>(O, proj_w, PART, 4096, 4096);
  k_reduce_ln<64><<<25, 256, 0, stream>>>(PART, proj_b, T, ln_g, ln_b, T, H);

  // 3. FFN branch: ff1 KC=256 -> S=16, grid 64x16
  k_gemm<256><<<dim3(64, 16), 256, 0, stream>>>(H, ff1_w, PART, 4096, 16384);
  k_reduce<16, 1, 0><<<400, 256, 0, stream>>>(PART, ff1_b, nullptr, G, 16384);
  // ff2 KC=256 -> S=64, grid 16x64
  k_gemm<256><<<dim3(16, 64), 256, 0, stream>>>(G, ff2_w, PART, 16384, 4096);
  k_reduce<64, 0, 1><<<100, 256, 0, stream>>>(PART, ff2_b, T, out, 4096);
}

// Round 4
// 370.358 us; speedup vs baseline: 1.7038x; 1.7038x over previous
//
#include <hip/hip_runtime.h>
#include <math.h>

#define TOK 25

typedef __attribute__((address_space(1))) const void as1_void;
typedef __attribute__((address_space(3))) void as3_void;

__device__ __forceinline__ void gload_lds16(const float* gp, float* lp) {
  __builtin_amdgcn_global_load_lds((as1_void*)(const void*)gp,
                                   (as3_void*)(void*)lp, 16, 0, 0);
}

// ---------------- patchify: x[1,256,20,20] -> P[25][4096] (idx = c*16+kh*4+kw)
__global__ __launch_bounds__(256) void k_patchify(const float* __restrict__ x,
                                                  float* __restrict__ P) {
  int idx = blockIdx.x * 256 + threadIdx.x;  // 0..102399
  int n = idx >> 12;
  int rem = idx & 4095;
  int c = rem >> 4;
  int kh = (rem >> 2) & 3;
  int kw = rem & 3;
  int py = n / 5, px = n - py * 5;
  P[idx] = x[c * 400 + (py * 4 + kh) * 20 + (px * 4 + kw)];
}

// ---------------- streaming GEMM, W[K][Nout]; LDS-staged W via global_load_lds.
// block: 512 cols (2/lane), K-chunk KCV. partial[S][25][Nout].
template <int KCV>
__global__ __launch_bounds__(256, 3) void k_gemm_lds2(
    const float* __restrict__ A, const float* __restrict__ W,
    float* __restrict__ part, int K, int Nout) {
  __shared__ __align__(16) float As[TOK * KCV];
  __shared__ __align__(16) float Wb[2][8 * 512];
  const int tid = threadIdx.x;
  const int s = blockIdx.y;
  const int k0 = s * KCV;
  const int cbase = blockIdx.x * 512;
  // stage A-tile (25 x KCV)
  for (int i = tid; i < TOK * (KCV / 4); i += 256) {
    int r = i / (KCV / 4);
    int k4 = i - r * (KCV / 4);
    reinterpret_cast<float4*>(As)[i] =
        reinterpret_cast<const float4*>(A + (long)r * K + k0)[k4];
  }
  const int wv = tid >> 6;
  // prologue: stage k-block 0 into Wb[0]
  {
    const float* Ws = W + (long)k0 * Nout + cbase;
#pragma unroll
    for (int j = 0; j < 4; ++j) {
      int f = j * 256 + tid;
      const float* gp = Ws + (long)(f >> 7) * Nout + (f & 127) * 4;
      gload_lds16(gp, &Wb[0][0] + (j * 256 + wv * 64) * 4);
    }
  }
  float acc0[TOK], acc1[TOK];
#pragma unroll
  for (int r = 0; r < TOK; ++r) { acc0[r] = 0.f; acc1[r] = 0.f; }
  asm volatile("s_waitcnt lgkmcnt(0)" ::: "memory");  // A-tile stores drained
  __builtin_amdgcn_s_barrier();
  const int NITER = KCV / 8;
  for (int kb = 0; kb < NITER; ++kb) {
    if (kb + 1 < NITER) {
      const float* Ws = W + (long)(k0 + (kb + 1) * 8) * Nout + cbase;
      float* lbase = &Wb[(kb + 1) & 1][0];
#pragma unroll
      for (int j = 0; j < 4; ++j) {
        int f = j * 256 + tid;
        const float* gp = Ws + (long)(f >> 7) * Nout + (f & 127) * 4;
        gload_lds16(gp, lbase + (j * 256 + wv * 64) * 4);
      }
      asm volatile("s_waitcnt vmcnt(4)" ::: "memory");  // current buf landed
    } else {
      asm volatile("s_waitcnt vmcnt(0)" ::: "memory");
    }
    __builtin_amdgcn_s_barrier();  // all waves' stages for cur buf complete
    const float* Wc = &Wb[kb & 1][0];
    float w0[8], w1[8];
#pragma unroll
    for (int k = 0; k < 8; ++k) {
      w0[k] = Wc[k * 512 + tid];
      w1[k] = Wc[k * 512 + 256 + tid];
    }
    const float* ap = As + kb * 8;
#pragma unroll
    for (int r = 0; r < TOK; ++r) {
      float4 a0 = *reinterpret_cast<const float4*>(ap + r * KCV);
      float4 a1 = *reinterpret_cast<const float4*>(ap + r * KCV + 4);
      float av[8] = {a0.x, a0.y, a0.z, a0.w, a1.x, a1.y, a1.z, a1.w};
#pragma unroll
      for (int k = 0; k < 8; ++k) {
        acc0[r] = fmaf(av[k], w0[k], acc0[r]);
        acc1[r] = fmaf(av[k], w1[k], acc1[r]);
      }
    }
    __builtin_amdgcn_s_barrier();  // done reading cur before it's restaged
  }
  float* pp = part + ((long)s * TOK) * Nout + cbase + tid;
#pragma unroll
  for (int r = 0; r < TOK; ++r) {
    pp[(long)r * Nout] = acc0[r];
    pp[(long)r * Nout + 256] = acc1[r];
  }
}

// ---------------- GEMM, W in [Nout][K] layout (conv weight) — R2-proven path
template <int KCV>
__global__ __launch_bounds__(256) void k_gemm_wt(const float* __restrict__ A,
                                                 const float* __restrict__ W,
                                                 float* __restrict__ part,
                                                 int K, int Nout) {
  __shared__ float As[TOK * KCV];
  const int s = blockIdx.y;
  const int k0 = s * KCV;
  const int o = blockIdx.x * 256 + threadIdx.x;
  for (int i = threadIdx.x; i < TOK * (KCV / 4); i += 256) {
    int r = i / (KCV / 4);
    int k4 = i - r * (KCV / 4);
    reinterpret_cast<float4*>(As)[i] =
        reinterpret_cast<const float4*>(A + (long)r * K + k0)[k4];
  }
  __syncthreads();
  float acc[TOK];
#pragma unroll
  for (int r = 0; r < TOK; ++r) acc[r] = 0.f;
  const float* wp = W + (long)o * K + k0;
  for (int kk = 0; kk < KCV; kk += 8) {
    float4 wa = *reinterpret_cast<const float4*>(wp + kk);
    float4 wb = *reinterpret_cast<const float4*>(wp + kk + 4);
#pragma unroll
    for (int r = 0; r < TOK; ++r) {
      float4 a = *reinterpret_cast<const float4*>(&As[r * KCV + kk]);
      float4 a2 = *reinterpret_cast<const float4*>(&As[r * KCV + kk + 4]);
      acc[r] = fmaf(a.x, wa.x, acc[r]);
      acc[r] = fmaf(a.y, wa.y, acc[r]);
      acc[r] = fmaf(a.z, wa.z, acc[r]);
      acc[r] = fmaf(a.w, wa.w, acc[r]);
      acc[r] = fmaf(a2.x, wb.x, acc[r]);
      acc[r] = fmaf(a2.y, wb.y, acc[r]);
      acc[r] = fmaf(a2.z, wb.z, acc[r]);
      acc[r] = fmaf(a2.w, wb.w, acc[r]);
    }
  }
  float* pp = part + ((long)s * TOK) * Nout + o;
#pragma unroll
  for (int r = 0; r < TOK; ++r) pp[(long)r * Nout] = acc[r];
}

// ---------------- reduce partials + bias (+gelu) (+residual), float4 per thread
template <int S, int GELU, int RES>
__global__ __launch_bounds__(256) void k_reduce(const float* __restrict__ part,
                                                const float* __restrict__ bias,
                                                const float* __restrict__ res,
                                                float* __restrict__ out,
                                                int Nout) {
  long idx4 = (long)blockIdx.x * 256 + threadIdx.x;  // float4 index
  int c4 = (int)(idx4 % (Nout >> 2));
  const long stride4 = (long)TOK * (Nout >> 2);
  const float4* p4 = reinterpret_cast<const float4*>(part) + idx4;
  float4 v = {0.f, 0.f, 0.f, 0.f};
#pragma unroll 16
  for (int s = 0; s < S; ++s) {
    float4 t = p4[s * stride4];
    v.x += t.x; v.y += t.y; v.z += t.z; v.w += t.w;
  }
  float4 bb = reinterpret_cast<const float4*>(bias)[c4];
  v.x += bb.x; v.y += bb.y; v.z += bb.z; v.w += bb.w;
  if (GELU) {
    v.x = 0.5f * v.x * (1.f + erff(v.x * 0.70710678118654752f));
    v.y = 0.5f * v.y * (1.f + erff(v.y * 0.70710678118654752f));
    v.z = 0.5f * v.z * (1.f + erff(v.z * 0.70710678118654752f));
    v.w = 0.5f * v.w * (1.f + erff(v.w * 0.70710678118654752f));
  }
  if (RES) {
    float4 rr = reinterpret_cast<const float4*>(res)[idx4];
    v.x += rr.x; v.y += rr.y; v.z += rr.z; v.w += rr.w;
  }
  reinterpret_cast<float4*>(out)[idx4] = v;
}

// ---------------- LayerNorm over 4096, one block per token
__global__ __launch_bounds__(256) void k_ln(const float* __restrict__ t,
                                            const float* __restrict__ g,
                                            const float* __restrict__ b,
                                            float* __restrict__ h) {
  const int n = blockIdx.x;
  const float4* row = reinterpret_cast<const float4*>(t + n * 4096);
  float s = 0.f, s2 = 0.f;
  float4 vbuf[4];
#pragma unroll
  for (int it = 0; it < 4; ++it) {
    float4 v = row[threadIdx.x + it * 256];
    vbuf[it] = v;
    s += v.x + v.y + v.z + v.w;
    s2 += v.x * v.x + v.y * v.y + v.z * v.z + v.w * v.w;
  }
#pragma unroll
  for (int off = 32; off >= 1; off >>= 1) {
    s += __shfl_down(s, off);
    s2 += __shfl_down(s2, off);
  }
  __shared__ float red[8];
  if ((threadIdx.x & 63) == 0) {
    red[threadIdx.x >> 6] = s;
    red[4 + (threadIdx.x >> 6)] = s2;
  }
  __syncthreads();
  float st = red[0] + red[1] + red[2] + red[3];
  float s2t = red[4] + red[5] + red[6] + red[7];
  float mean = st * (1.f / 4096.f);
  float var = s2t * (1.f / 4096.f) - mean * mean;
  float rstd = rsqrtf(var + 1e-5f);
  const float4* g4 = reinterpret_cast<const float4*>(g);
  const float4* b4 = reinterpret_cast<const float4*>(b);
  float4* h4 = reinterpret_cast<float4*>(h + n * 4096);
#pragma unroll
  for (int it = 0; it < 4; ++it) {
    int i = threadIdx.x + it * 256;
    float4 v = vbuf[it];
    float4 gg = g4[i];
    float4 bb = b4[i];
    float4 o;
    o.x = (v.x - mean) * rstd * gg.x + bb.x;
    o.y = (v.y - mean) * rstd * gg.y + bb.y;
    o.z = (v.z - mean) * rstd * gg.z + bb.z;
    o.w = (v.w - mean) * rstd * gg.w + bb.w;
    h4[i] = o;
  }
}

// ---------------- attention: QK^T + softmax/64 -> att[16][25][25]
__global__ __launch_bounds__(256) void k_attn_qk(const float* __restrict__ qkv,
                                                 float* __restrict__ att) {
  const int head = blockIdx.x;
  __shared__ float q[TOK][260];
  __shared__ float k[TOK][260];
  __shared__ float e[TOK][TOK];
  const int d = threadIdx.x;
#pragma unroll
  for (int n = 0; n < TOK; ++n) {
    const long base = (long)n * 12288 + (head * 256 + d) * 3;
    q[n][d] = qkv[base];
    k[n][d] = qkv[base + 1];
  }
  __syncthreads();
  for (int p = threadIdx.x; p < TOK * TOK; p += 256) {
    int i = p / TOK, j = p - i * TOK;
    float acc = 0.f;
#pragma unroll
    for (int kk = 0; kk < 256; kk += 4) {
      float4 a = *reinterpret_cast<const float4*>(&q[i][kk]);
      float4 bb = *reinterpret_cast<const float4*>(&k[j][kk]);
      acc = fmaf(a.x, bb.x, acc);
      acc = fmaf(a.y, bb.y, acc);
      acc = fmaf(a.z, bb.z, acc);
      acc = fmaf(a.w, bb.w, acc);
    }
    e[i][j] = acc;
  }
  __syncthreads();
  if (threadIdx.x < TOK) {
    const int i = threadIdx.x;
    float m = -1e30f;
    for (int j = 0; j < TOK; ++j) m = fmaxf(m, e[i][j]);
    float ssum = 0.f;
    float ex[TOK];
#pragma unroll
    for (int j = 0; j < TOK; ++j) {
      ex[j] = expf(e[i][j] - m);
      ssum += ex[j];
    }
    float inv = 1.f / (ssum * 64.f);  // softmax then /sqrt(4096)
#pragma unroll
    for (int j = 0; j < TOK; ++j) att[head * 625 + i * TOK + j] = ex[j] * inv;
  }
}

// ---------------- attention: att @ V -> o[25][4096]
__global__ __launch_bounds__(256) void k_attn_pv(const float* __restrict__ qkv,
                                                 const float* __restrict__ att,
                                                 float* __restrict__ o) {
  const int head = blockIdx.x;
  const int d = threadIdx.x;
  __shared__ float a[TOK * TOK];
  for (int i = threadIdx.x; i < TOK * TOK; i += 256) a[i] = att[head * 625 + i];
  __syncthreads();
  float acc[TOK];
#pragma unroll
  for (int i = 0; i < TOK; ++i) acc[i] = 0.f;
#pragma unroll
  for (int j = 0; j < TOK; ++j) {
    float vv = qkv[(long)j * 12288 + (head * 256 + d) * 3 + 2];
#pragma unroll
    for (int i = 0; i < TOK; ++i) acc[i] = fmaf(a[i * TOK + j], vv, acc[i]);
  }
#pragma unroll
  for (int i = 0; i < TOK; ++i) o[(long)i * 4096 + head * 256 + d] = acc[i];
}

extern "C" void kernel_launch(void* const* d_in, const int* in_sizes, int n_in,
                              void* d_out, int out_size, void* d_ws, size_t ws_size,
                              hipStream_t stream) {
  (void)in_sizes; (void)n_in; (void)out_size;
  const float* x      = (const float*)d_in[0];
  const float* pe_w   = (const float*)d_in[1];
  const float* pe_b   = (const float*)d_in[2];
  const float* pos    = (const float*)d_in[3];
  const float* ln_g   = (const float*)d_in[4];
  const float* ln_b   = (const float*)d_in[5];
  const float* qkv_w  = (const float*)d_in[6];
  const float* qkv_b  = (const float*)d_in[7];
  const float* proj_w = (const float*)d_in[8];
  const float* proj_b = (const float*)d_in[9];
  const float* ff1_w  = (const float*)d_in[10];
  const float* ff1_b  = (const float*)d_in[11];
  const float* ff2_w  = (const float*)d_in[12];
  const float* ff2_b  = (const float*)d_in[13];
  float* out = (float*)d_out;

  float* ws = (float*)d_ws;
  float* P    = ws;             // 102400
  float* T    = ws + 102400;    // 102400
  float* H    = ws + 204800;    // 102400
  float* QKV  = ws + 307200;    // 307200
  float* O    = ws + 614400;    // 102400
  float* G    = ws + 716800;    // 409600
  float* ATT  = ws + 1126400;   // 10000
  float* PART = ws + 1136400;
  const long avail = (long)(ws_size / 4) - 1136400;
  const bool big = avail >= 13107200;  // 52.4 MB of partials available?

  // 1. patch embedding (R2-proven path)
  k_patchify<<<400, 256, 0, stream>>>(x, P);
  k_gemm_wt<64><<<dim3(16, 64), 256, 0, stream>>>(P, pe_w, PART, 4096, 4096);
  k_reduce<64, 0, 1><<<100, 256, 0, stream>>>(PART, pe_b, pos, T, 4096);
  k_ln<<<25, 256, 0, stream>>>(T, ln_g, ln_b, H);

  // 2. attention branch: qkv KC=128 -> S=32 (39.3 MB partials, proven fit)
  k_gemm_lds2<128><<<dim3(24, 32), 256, 0, stream>>>(H, qkv_w, PART, 4096, 12288);
  k_reduce<32, 0, 0><<<300, 256, 0, stream>>>(PART, qkv_b, nullptr, QKV, 12288);
  k_attn_qk<<<16, 256, 0, stream>>>(QKV, ATT);
  k_attn_pv<<<16, 256, 0, stream>>>(QKV, ATT, O);
  if (big) {
    k_gemm_lds2<32><<<dim3(8, 128), 256, 0, stream>>>(O, proj_w, PART, 4096, 4096);
    k_reduce<128, 0, 1><<<100, 256, 0, stream>>>(PART, proj_b, T, T, 4096);
  } else {
    k_gemm_lds2<64><<<dim3(8, 64), 256, 0, stream>>>(O, proj_w, PART, 4096, 4096);
    k_reduce<64, 0, 1><<<100, 256, 0, stream>>>(PART, proj_b, T, T, 4096);
  }
  k_ln<<<25, 256, 0, stream>>>(T, ln_g, ln_b, H);

  // 3. FFN branch
  if (big) {
    k_gemm_lds2<128><<<dim3(32, 32), 256, 0, stream>>>(H, ff1_w, PART, 4096, 16384);
    k_reduce<32, 1, 0><<<400, 256, 0, stream>>>(PART, ff1_b, nullptr, G, 16384);
    k_gemm_lds2<128><<<dim3(8, 128), 256, 0, stream>>>(G, ff2_w, PART, 16384, 4096);
    k_reduce<128, 0, 1><<<100, 256, 0, stream>>>(PART, ff2_b, T, out, 4096);
  } else {
    k_gemm_lds2<256><<<dim3(32, 16), 256, 0, stream>>>(H, ff1_w, PART, 4096, 16384);
    k_reduce<16, 1, 0><<<400, 256, 0, stream>>>(PART, ff1_b, nullptr, G, 16384);
    k_gemm_lds2<256><<<dim3(8, 64), 256, 0, stream>>>(G, ff2_w, PART, 16384, 4096);
    k_reduce<64, 0, 1><<<100, 256, 0, stream>>>(PART, ff2_b, T, out, 4096);
  }
}

// Round 5
// 359.957 us; speedup vs baseline: 1.7530x; 1.0289x over previous
//
#include <hip/hip_runtime.h>
#include <math.h>

#define TOK 25

typedef __attribute__((address_space(1))) const void as1_void;
typedef __attribute__((address_space(3))) void as3_void;

__device__ __forceinline__ void gload_lds16(const float* gp, float* lp) {
  __builtin_amdgcn_global_load_lds((as1_void*)(const void*)gp,
                                   (as3_void*)(void*)lp, 16, 0, 0);
}

// ---------------- patchify: x[1,256,20,20] -> P[25][4096] (idx = c*16+kh*4+kw)
__global__ __launch_bounds__(256) void k_patchify(const float* __restrict__ x,
                                                  float* __restrict__ P) {
  int idx = blockIdx.x * 256 + threadIdx.x;  // 0..102399
  int n = idx >> 12;
  int rem = idx & 4095;
  int c = rem >> 4;
  int kh = (rem >> 2) & 3;
  int kw = rem & 3;
  int py = n / 5, px = n - py * 5;
  P[idx] = x[c * 400 + (py * 4 + kh) * 20 + (px * 4 + kw)];
}

// stage one 8-k x 1024-col W tile (32KB) into LDS via global_load_lds
__device__ __forceinline__ void stage8(const float* Ws, float* lbase, int Nout,
                                       int tid, int wv) {
#pragma unroll
  for (int j = 0; j < 8; ++j)
    gload_lds16(Ws + (long)j * Nout + tid * 4, lbase + j * 1024 + wv * 256);
}

// ---------------- streaming GEMM, W[K][Nout]; 1024 cols/block (4/lane),
// double-buffered 8-k W tiles via global_load_lds. partial[S][25][Nout].
template <int KCV>
__global__ __launch_bounds__(256, 2) void k_gemm_l4(
    const float* __restrict__ A, const float* __restrict__ W,
    float* __restrict__ part, int K, int Nout) {
  __shared__ __align__(16) float As[TOK * KCV];
  __shared__ __align__(16) float Wb[2][8 * 1024];
  const int tid = threadIdx.x;
  const int s = blockIdx.y;
  const int k0 = s * KCV;
  const int cbase = blockIdx.x * 1024;
  const int wv = tid >> 6;
  // stage A-tile (25 x KCV)
  for (int i = tid; i < TOK * (KCV / 4); i += 256) {
    int r = i / (KCV / 4);
    int k4 = i - r * (KCV / 4);
    reinterpret_cast<float4*>(As)[i] =
        reinterpret_cast<const float4*>(A + (long)r * K + k0)[k4];
  }
  float4 acc[TOK];
#pragma unroll
  for (int r = 0; r < TOK; ++r) acc[r] = make_float4(0.f, 0.f, 0.f, 0.f);
  // prologue: stage k-block 0 into Wb[0]
  stage8(W + (long)k0 * Nout + cbase, &Wb[0][0], Nout, tid, wv);
  asm volatile("s_waitcnt lgkmcnt(0)" ::: "memory");  // As ds_writes drained
  __builtin_amdgcn_s_barrier();
  const int NITER = KCV / 8;
  for (int kb = 0; kb < NITER; ++kb) {
    if (kb + 1 < NITER) {
      stage8(W + (long)(k0 + (kb + 1) * 8) * Nout + cbase, &Wb[(kb + 1) & 1][0],
             Nout, tid, wv);
      asm volatile("s_waitcnt vmcnt(8)" ::: "memory");  // kb's tile landed
    } else {
      asm volatile("s_waitcnt vmcnt(0)" ::: "memory");
    }
    __builtin_amdgcn_s_barrier();  // all waves' stages for cur tile complete
    const float* Wc = &Wb[kb & 1][0];
    float4 w[8];
#pragma unroll
    for (int k = 0; k < 8; ++k)
      w[k] = *reinterpret_cast<const float4*>(&Wc[k * 1024 + tid * 4]);
    const float* ap = As + kb * 8;
#pragma unroll
    for (int r = 0; r < TOK; ++r) {
      float4 a0 = *reinterpret_cast<const float4*>(ap + r * KCV);
      float4 a1 = *reinterpret_cast<const float4*>(ap + r * KCV + 4);
      float av[8] = {a0.x, a0.y, a0.z, a0.w, a1.x, a1.y, a1.z, a1.w};
#pragma unroll
      for (int k = 0; k < 8; ++k) {
        acc[r].x = fmaf(av[k], w[k].x, acc[r].x);
        acc[r].y = fmaf(av[k], w[k].y, acc[r].y);
        acc[r].z = fmaf(av[k], w[k].z, acc[r].z);
        acc[r].w = fmaf(av[k], w[k].w, acc[r].w);
      }
    }
    __builtin_amdgcn_s_barrier();  // done reading cur before it's restaged
  }
  float4* pp =
      reinterpret_cast<float4*>(part + ((long)s * TOK) * Nout + cbase) + tid;
  const long ld4 = Nout >> 2;
#pragma unroll
  for (int r = 0; r < TOK; ++r) pp[(long)r * ld4] = acc[r];
}

// ---------------- GEMM, W in [Nout][K] layout (conv weight) — R2-proven path
template <int KCV>
__global__ __launch_bounds__(256) void k_gemm_wt(const float* __restrict__ A,
                                                 const float* __restrict__ W,
                                                 float* __restrict__ part,
                                                 int K, int Nout) {
  __shared__ float As[TOK * KCV];
  const int s = blockIdx.y;
  const int k0 = s * KCV;
  const int o = blockIdx.x * 256 + threadIdx.x;
  for (int i = threadIdx.x; i < TOK * (KCV / 4); i += 256) {
    int r = i / (KCV / 4);
    int k4 = i - r * (KCV / 4);
    reinterpret_cast<float4*>(As)[i] =
        reinterpret_cast<const float4*>(A + (long)r * K + k0)[k4];
  }
  __syncthreads();
  float acc[TOK];
#pragma unroll
  for (int r = 0; r < TOK; ++r) acc[r] = 0.f;
  const float* wp = W + (long)o * K + k0;
  for (int kk = 0; kk < KCV; kk += 8) {
    float4 wa = *reinterpret_cast<const float4*>(wp + kk);
    float4 wb = *reinterpret_cast<const float4*>(wp + kk + 4);
#pragma unroll
    for (int r = 0; r < TOK; ++r) {
      float4 a = *reinterpret_cast<const float4*>(&As[r * KCV + kk]);
      float4 a2 = *reinterpret_cast<const float4*>(&As[r * KCV + kk + 4]);
      acc[r] = fmaf(a.x, wa.x, acc[r]);
      acc[r] = fmaf(a.y, wa.y, acc[r]);
      acc[r] = fmaf(a.z, wa.z, acc[r]);
      acc[r] = fmaf(a.w, wa.w, acc[r]);
      acc[r] = fmaf(a2.x, wb.x, acc[r]);
      acc[r] = fmaf(a2.y, wb.y, acc[r]);
      acc[r] = fmaf(a2.z, wb.z, acc[r]);
      acc[r] = fmaf(a2.w, wb.w, acc[r]);
    }
  }
  float* pp = part + ((long)s * TOK) * Nout + o;
#pragma unroll
  for (int r = 0; r < TOK; ++r) pp[(long)r * Nout] = acc[r];
}

// ---------------- reduce partials + bias (+gelu) (+residual), float4 per thread
template <int S, int GELU, int RES>
__global__ __launch_bounds__(256) void k_reduce(const float* __restrict__ part,
                                                const float* __restrict__ bias,
                                                const float* __restrict__ res,
                                                float* __restrict__ out,
                                                int Nout) {
  long idx4 = (long)blockIdx.x * 256 + threadIdx.x;  // float4 index
  int c4 = (int)(idx4 % (Nout >> 2));
  const long stride4 = (long)TOK * (Nout >> 2);
  const float4* p4 = reinterpret_cast<const float4*>(part) + idx4;
  float4 v = {0.f, 0.f, 0.f, 0.f};
#pragma unroll 16
  for (int s = 0; s < S; ++s) {
    float4 t = p4[s * stride4];
    v.x += t.x; v.y += t.y; v.z += t.z; v.w += t.w;
  }
  float4 bb = reinterpret_cast<const float4*>(bias)[c4];
  v.x += bb.x; v.y += bb.y; v.z += bb.z; v.w += bb.w;
  if (GELU) {
    v.x = 0.5f * v.x * (1.f + erff(v.x * 0.70710678118654752f));
    v.y = 0.5f * v.y * (1.f + erff(v.y * 0.70710678118654752f));
    v.z = 0.5f * v.z * (1.f + erff(v.z * 0.70710678118654752f));
    v.w = 0.5f * v.w * (1.f + erff(v.w * 0.70710678118654752f));
  }
  if (RES) {
    float4 rr = reinterpret_cast<const float4*>(res)[idx4];
    v.x += rr.x; v.y += rr.y; v.z += rr.z; v.w += rr.w;
  }
  reinterpret_cast<float4*>(out)[idx4] = v;
}

// ---------------- LayerNorm over 4096, one block per token
__global__ __launch_bounds__(256) void k_ln(const float* __restrict__ t,
                                            const float* __restrict__ g,
                                            const float* __restrict__ b,
                                            float* __restrict__ h) {
  const int n = blockIdx.x;
  const float4* row = reinterpret_cast<const float4*>(t + n * 4096);
  float s = 0.f, s2 = 0.f;
  float4 vbuf[4];
#pragma unroll
  for (int it = 0; it < 4; ++it) {
    float4 v = row[threadIdx.x + it * 256];
    vbuf[it] = v;
    s += v.x + v.y + v.z + v.w;
    s2 += v.x * v.x + v.y * v.y + v.z * v.z + v.w * v.w;
  }
#pragma unroll
  for (int off = 32; off >= 1; off >>= 1) {
    s += __shfl_down(s, off);
    s2 += __shfl_down(s2, off);
  }
  __shared__ float red[8];
  if ((threadIdx.x & 63) == 0) {
    red[threadIdx.x >> 6] = s;
    red[4 + (threadIdx.x >> 6)] = s2;
  }
  __syncthreads();
  float st = red[0] + red[1] + red[2] + red[3];
  float s2t = red[4] + red[5] + red[6] + red[7];
  float mean = st * (1.f / 4096.f);
  float var = s2t * (1.f / 4096.f) - mean * mean;
  float rstd = rsqrtf(var + 1e-5f);
  const float4* g4 = reinterpret_cast<const float4*>(g);
  const float4* b4 = reinterpret_cast<const float4*>(b);
  float4* h4 = reinterpret_cast<float4*>(h + n * 4096);
#pragma unroll
  for (int it = 0; it < 4; ++it) {
    int i = threadIdx.x + it * 256;
    float4 v = vbuf[it];
    float4 gg = g4[i];
    float4 bb = b4[i];
    float4 o;
    o.x = (v.x - mean) * rstd * gg.x + bb.x;
    o.y = (v.y - mean) * rstd * gg.y + bb.y;
    o.z = (v.z - mean) * rstd * gg.z + bb.z;
    o.w = (v.w - mean) * rstd * gg.w + bb.w;
    h4[i] = o;
  }
}

// ---------------- attention: QK^T + softmax/64 -> att[16][25][25]
__global__ __launch_bounds__(256) void k_attn_qk(const float* __restrict__ qkv,
                                                 float* __restrict__ att) {
  const int head = blockIdx.x;
  __shared__ float q[TOK][260];
  __shared__ float k[TOK][260];
  __shared__ float e[TOK][TOK];
  const int d = threadIdx.x;
#pragma unroll
  for (int n = 0; n < TOK; ++n) {
    const long base = (long)n * 12288 + (head * 256 + d) * 3;
    q[n][d] = qkv[base];
    k[n][d] = qkv[base + 1];
  }
  __syncthreads();
  for (int p = threadIdx.x; p < TOK * TOK; p += 256) {
    int i = p / TOK, j = p - i * TOK;
    float acc = 0.f;
#pragma unroll
    for (int kk = 0; kk < 256; kk += 4) {
      float4 a = *reinterpret_cast<const float4*>(&q[i][kk]);
      float4 bb = *reinterpret_cast<const float4*>(&k[j][kk]);
      acc = fmaf(a.x, bb.x, acc);
      acc = fmaf(a.y, bb.y, acc);
      acc = fmaf(a.z, bb.z, acc);
      acc = fmaf(a.w, bb.w, acc);
    }
    e[i][j] = acc;
  }
  __syncthreads();
  if (threadIdx.x < TOK) {
    const int i = threadIdx.x;
    float m = -1e30f;
    for (int j = 0; j < TOK; ++j) m = fmaxf(m, e[i][j]);
    float ssum = 0.f;
    float ex[TOK];
#pragma unroll
    for (int j = 0; j < TOK; ++j) {
      ex[j] = expf(e[i][j] - m);
      ssum += ex[j];
    }
    float inv = 1.f / (ssum * 64.f);  // softmax then /sqrt(4096)
#pragma unroll
    for (int j = 0; j < TOK; ++j) att[head * 625 + i * TOK + j] = ex[j] * inv;
  }
}

// ---------------- attention: att @ V -> o[25][4096]
__global__ __launch_bounds__(256) void k_attn_pv(const float* __restrict__ qkv,
                                                 const float* __restrict__ att,
                                                 float* __restrict__ o) {
  const int head = blockIdx.x;
  const int d = threadIdx.x;
  __shared__ float a[TOK * TOK];
  for (int i = threadIdx.x; i < TOK * TOK; i += 256) a[i] = att[head * 625 + i];
  __syncthreads();
  float acc[TOK];
#pragma unroll
  for (int i = 0; i < TOK; ++i) acc[i] = 0.f;
#pragma unroll
  for (int j = 0; j < TOK; ++j) {
    float vv = qkv[(long)j * 12288 + (head * 256 + d) * 3 + 2];
#pragma unroll
    for (int i = 0; i < TOK; ++i) acc[i] = fmaf(a[i * TOK + j], vv, acc[i]);
  }
#pragma unroll
  for (int i = 0; i < TOK; ++i) o[(long)i * 4096 + head * 256 + d] = acc[i];
}

extern "C" void kernel_launch(void* const* d_in, const int* in_sizes, int n_in,
                              void* d_out, int out_size, void* d_ws, size_t ws_size,
                              hipStream_t stream) {
  (void)in_sizes; (void)n_in; (void)out_size;
  const float* x      = (const float*)d_in[0];
  const float* pe_w   = (const float*)d_in[1];
  const float* pe_b   = (const float*)d_in[2];
  const float* pos    = (const float*)d_in[3];
  const float* ln_g   = (const float*)d_in[4];
  const float* ln_b   = (const float*)d_in[5];
  const float* qkv_w  = (const float*)d_in[6];
  const float* qkv_b  = (const float*)d_in[7];
  const float* proj_w = (const float*)d_in[8];
  const float* proj_b = (const float*)d_in[9];
  const float* ff1_w  = (const float*)d_in[10];
  const float* ff1_b  = (const float*)d_in[11];
  const float* ff2_w  = (const float*)d_in[12];
  const float* ff2_b  = (const float*)d_in[13];
  float* out = (float*)d_out;

  float* ws = (float*)d_ws;
  float* P    = ws;             // 102400
  float* T    = ws + 102400;    // 102400
  float* H    = ws + 204800;    // 102400
  float* QKV  = ws + 307200;    // 307200
  float* O    = ws + 614400;    // 102400
  float* G    = ws + 716800;    // 409600
  float* ATT  = ws + 1126400;   // 10000
  float* PART = ws + 1136400;
  const long avail = (long)(ws_size / 4) - 1136400;
  const bool fine = avail >= 26214400;    // ff1 S=64 partials (105 MB)
  const bool mid  = avail >= 13107200;    // R4-proven sizes (52.4 MB)

  // 1. patch embedding (R2-proven path)
  k_patchify<<<400, 256, 0, stream>>>(x, P);
  k_gemm_wt<64><<<dim3(16, 64), 256, 0, stream>>>(P, pe_w, PART, 4096, 4096);
  k_reduce<64, 0, 1><<<100, 256, 0, stream>>>(PART, pe_b, pos, T, 4096);
  k_ln<<<25, 256, 0, stream>>>(T, ln_g, ln_b, H);

  // 2. attention branch
  if (fine) {
    k_gemm_l4<64><<<dim3(12, 64), 256, 0, stream>>>(H, qkv_w, PART, 4096, 12288);
    k_reduce<64, 0, 0><<<300, 256, 0, stream>>>(PART, qkv_b, nullptr, QKV, 12288);
  } else if (mid) {
    k_gemm_l4<128><<<dim3(12, 32), 256, 0, stream>>>(H, qkv_w, PART, 4096, 12288);
    k_reduce<32, 0, 0><<<300, 256, 0, stream>>>(PART, qkv_b, nullptr, QKV, 12288);
  } else {
    k_gemm_l4<256><<<dim3(12, 16), 256, 0, stream>>>(H, qkv_w, PART, 4096, 12288);
    k_reduce<16, 0, 0><<<300, 256, 0, stream>>>(PART, qkv_b, nullptr, QKV, 12288);
  }
  k_attn_qk<<<16, 256, 0, stream>>>(QKV, ATT);
  k_attn_pv<<<16, 256, 0, stream>>>(QKV, ATT, O);
  if (fine) {
    k_gemm_l4<32><<<dim3(4, 128), 256, 0, stream>>>(O, proj_w, PART, 4096, 4096);
    k_reduce<128, 0, 1><<<100, 256, 0, stream>>>(PART, proj_b, T, T, 4096);
  } else if (mid) {
    k_gemm_l4<64><<<dim3(4, 64), 256, 0, stream>>>(O, proj_w, PART, 4096, 4096);
    k_reduce<64, 0, 1><<<100, 256, 0, stream>>>(PART, proj_b, T, T, 4096);
  } else {
    k_gemm_l4<128><<<dim3(4, 32), 256, 0, stream>>>(O, proj_w, PART, 4096, 4096);
    k_reduce<32, 0, 1><<<100, 256, 0, stream>>>(PART, proj_b, T, T, 4096);
  }
  k_ln<<<25, 256, 0, stream>>>(T, ln_g, ln_b, H);

  // 3. FFN branch
  if (fine) {
    k_gemm_l4<64><<<dim3(16, 64), 256, 0, stream>>>(H, ff1_w, PART, 4096, 16384);
    k_reduce<64, 1, 0><<<400, 256, 0, stream>>>(PART, ff1_b, nullptr, G, 16384);
    k_gemm_l4<128><<<dim3(4, 128), 256, 0, stream>>>(G, ff2_w, PART, 16384, 4096);
    k_reduce<128, 0, 1><<<100, 256, 0, stream>>>(PART, ff2_b, T, out, 4096);
  } else if (mid) {
    k_gemm_l4<128><<<dim3(16, 32), 256, 0, stream>>>(H, ff1_w, PART, 4096, 16384);
    k_reduce<32, 1, 0><<<400, 256, 0, stream>>>(PART, ff1_b, nullptr, G, 16384);
    k_gemm_l4<128><<<dim3(4, 128), 256, 0, stream>>>(G, ff2_w, PART, 16384, 4096);
    k_reduce<128, 0, 1><<<100, 256, 0, stream>>>(PART, ff2_b, T, out, 4096);
  } else {
    k_gemm_l4<256><<<dim3(16, 16), 256, 0, stream>>>(H, ff1_w, PART, 4096, 16384);
    k_reduce<16, 1, 0><<<400, 256, 0, stream>>>(PART, ff1_b, nullptr, G, 16384);
    k_gemm_l4<256><<<dim3(4, 64), 256, 0, stream>>>(G, ff2_w, PART, 16384, 4096);
    k_reduce<64, 0, 1><<<100, 256, 0, stream>>>(PART, ff2_b, T, out, 4096);
  }
}

// Round 6
// 329.418 us; speedup vs baseline: 1.9155x; 1.0927x over previous
//
#include <hip/hip_runtime.h>
#include <math.h>

#define TOK 25

typedef __attribute__((ext_vector_type(8))) short short8_t;   // 8 bf16
typedef __attribute__((ext_vector_type(4))) float f32x4_t;    // MFMA acc

// fp32 -> bf16 (round-to-nearest-even), bit pattern as short
__device__ __forceinline__ short bf16r(float f) {
  union { float f; unsigned u; } v;
  v.f = f;
  unsigned r = v.u + 0x7FFFu + ((v.u >> 16) & 1u);
  return (short)(r >> 16);
}

// ---------------- patchify: x[1,256,20,20] -> P[25][4096] (idx = c*16+kh*4+kw)
__global__ __launch_bounds__(256) void k_patchify(const float* __restrict__ x,
                                                  float* __restrict__ P) {
  int idx = blockIdx.x * 256 + threadIdx.x;  // 0..102399
  int n = idx >> 12;
  int rem = idx & 4095;
  int c = rem >> 4;
  int kh = (rem >> 2) & 3;
  int kw = rem & 3;
  int py = n / 5, px = n - py * 5;
  P[idx] = x[c * 400 + (py * 4 + kh) * 20 + (px * 4 + kw)];
}

// ---------------- MFMA GEMM: part[s][25][N] = A[25][K-chunk] * W-chunk
// One wave owns 16 output cols x KC k-range. No LDS, no barriers.
// WT=0: W[K][N] (linear layers).  WT=1: W[N][K] (conv weight, B=W^T).
// A rows 16..31 of tile 1: rows >= 25 are clamped to row 0 and discarded.
template <int KC, int WT>
__global__ __launch_bounds__(256) void k_mfma(const float* __restrict__ A,
                                              const float* __restrict__ W,
                                              float* __restrict__ part,
                                              int K, int N) {
  const int lane = threadIdx.x & 63;
  const int wv = threadIdx.x >> 6;
  const int c0 = (blockIdx.x * 4 + wv) * 16;
  const int s = blockIdx.y;
  const int k0 = s * KC;
  const int lm = lane & 15;  // row (A) / col (B) within 16
  const int lg = lane >> 4;  // k-group (8 elements each)
  const int col = c0 + lm;
  const int r1 = 16 + lm;
  const int r1c = (r1 < TOK) ? r1 : 0;  // clamp; tile-1 rows >=25 discarded

  f32x4_t acc0 = {0.f, 0.f, 0.f, 0.f};
  f32x4_t acc1 = {0.f, 0.f, 0.f, 0.f};

#pragma unroll 2
  for (int ks = 0; ks < KC; ks += 32) {
    const int kb = k0 + ks + lg * 8;
    // ---- B fragment: 8 k-elements for this col
    float bf[8];
    if (WT) {
      const float* bp = W + (long)col * K + kb;
      float4 b0 = *reinterpret_cast<const float4*>(bp);
      float4 b1 = *reinterpret_cast<const float4*>(bp + 4);
      bf[0] = b0.x; bf[1] = b0.y; bf[2] = b0.z; bf[3] = b0.w;
      bf[4] = b1.x; bf[5] = b1.y; bf[6] = b1.z; bf[7] = b1.w;
    } else {
      const float* bp = W + (long)kb * N + col;
#pragma unroll
      for (int j = 0; j < 8; ++j) bf[j] = bp[(long)j * N];
    }
    // ---- A fragments (global, L2-resident)
    const float* ap0 = A + (long)lm * K + kb;
    const float* ap1 = A + (long)r1c * K + kb;
    float4 a00 = *reinterpret_cast<const float4*>(ap0);
    float4 a01 = *reinterpret_cast<const float4*>(ap0 + 4);
    float4 a10 = *reinterpret_cast<const float4*>(ap1);
    float4 a11 = *reinterpret_cast<const float4*>(ap1 + 4);
    float af0[8] = {a00.x, a00.y, a00.z, a00.w, a01.x, a01.y, a01.z, a01.w};
    float af1[8] = {a10.x, a10.y, a10.z, a10.w, a11.x, a11.y, a11.z, a11.w};
    // ---- convert to bf16 fragments
    short8_t av0, av1, bv;
#pragma unroll
    for (int j = 0; j < 8; ++j) {
      bv[j] = bf16r(bf[j]);
      av0[j] = bf16r(af0[j]);
      av1[j] = bf16r(af1[j]);
    }
    acc0 = __builtin_amdgcn_mfma_f32_16x16x32_bf16(av0, bv, acc0, 0, 0, 0);
    acc1 = __builtin_amdgcn_mfma_f32_16x16x32_bf16(av1, bv, acc1, 0, 0, 0);
  }
  // ---- store: C row = lg*4 + reg (tile0), 16 + lg*4 + reg (tile1); col = lm
  float* pp = part + ((long)s * TOK) * N + col;
#pragma unroll
  for (int r = 0; r < 4; ++r) {
    int row0 = lg * 4 + r;
    pp[(long)row0 * N] = acc0[r];
    int row1 = 16 + lg * 4 + r;
    if (row1 < TOK) pp[(long)row1 * N] = acc1[r];
  }
}

// ---------------- reduce partials + bias (+gelu) (+residual), float4 per thread
template <int S, int GELU, int RES>
__global__ __launch_bounds__(256) void k_reduce(const float* __restrict__ part,
                                                const float* __restrict__ bias,
                                                const float* __restrict__ res,
                                                float* __restrict__ out,
                                                int Nout) {
  long idx4 = (long)blockIdx.x * 256 + threadIdx.x;  // float4 index
  int c4 = (int)(idx4 % (Nout >> 2));
  const long stride4 = (long)TOK * (Nout >> 2);
  const float4* p4 = reinterpret_cast<const float4*>(part) + idx4;
  float4 v = {0.f, 0.f, 0.f, 0.f};
#pragma unroll
  for (int s = 0; s < S; ++s) {
    float4 t = p4[s * stride4];
    v.x += t.x; v.y += t.y; v.z += t.z; v.w += t.w;
  }
  float4 bb = reinterpret_cast<const float4*>(bias)[c4];
  v.x += bb.x; v.y += bb.y; v.z += bb.z; v.w += bb.w;
  if (GELU) {
    v.x = 0.5f * v.x * (1.f + erff(v.x * 0.70710678118654752f));
    v.y = 0.5f * v.y * (1.f + erff(v.y * 0.70710678118654752f));
    v.z = 0.5f * v.z * (1.f + erff(v.z * 0.70710678118654752f));
    v.w = 0.5f * v.w * (1.f + erff(v.w * 0.70710678118654752f));
  }
  if (RES) {
    float4 rr = reinterpret_cast<const float4*>(res)[idx4];
    v.x += rr.x; v.y += rr.y; v.z += rr.z; v.w += rr.w;
  }
  reinterpret_cast<float4*>(out)[idx4] = v;
}

// ---------------- LayerNorm over 4096, one block per token
__global__ __launch_bounds__(256) void k_ln(const float* __restrict__ t,
                                            const float* __restrict__ g,
                                            const float* __restrict__ b,
                                            float* __restrict__ h) {
  const int n = blockIdx.x;
  const float4* row = reinterpret_cast<const float4*>(t + n * 4096);
  float s = 0.f, s2 = 0.f;
  float4 vbuf[4];
#pragma unroll
  for (int it = 0; it < 4; ++it) {
    float4 v = row[threadIdx.x + it * 256];
    vbuf[it] = v;
    s += v.x + v.y + v.z + v.w;
    s2 += v.x * v.x + v.y * v.y + v.z * v.z + v.w * v.w;
  }
#pragma unroll
  for (int off = 32; off >= 1; off >>= 1) {
    s += __shfl_down(s, off);
    s2 += __shfl_down(s2, off);
  }
  __shared__ float red[8];
  if ((threadIdx.x & 63) == 0) {
    red[threadIdx.x >> 6] = s;
    red[4 + (threadIdx.x >> 6)] = s2;
  }
  __syncthreads();
  float st = red[0] + red[1] + red[2] + red[3];
  float s2t = red[4] + red[5] + red[6] + red[7];
  float mean = st * (1.f / 4096.f);
  float var = s2t * (1.f / 4096.f) - mean * mean;
  float rstd = rsqrtf(var + 1e-5f);
  const float4* g4 = reinterpret_cast<const float4*>(g);
  const float4* b4 = reinterpret_cast<const float4*>(b);
  float4* h4 = reinterpret_cast<float4*>(h + n * 4096);
#pragma unroll
  for (int it = 0; it < 4; ++it) {
    int i = threadIdx.x + it * 256;
    float4 v = vbuf[it];
    float4 gg = g4[i];
    float4 bb = b4[i];
    float4 o;
    o.x = (v.x - mean) * rstd * gg.x + bb.x;
    o.y = (v.y - mean) * rstd * gg.y + bb.y;
    o.z = (v.z - mean) * rstd * gg.z + bb.z;
    o.w = (v.w - mean) * rstd * gg.w + bb.w;
    h4[i] = o;
  }
}

// ---------------- attention: QK^T + softmax/64 -> att[16][25][25]
__global__ __launch_bounds__(256) void k_attn_qk(const float* __restrict__ qkv,
                                                 float* __restrict__ att) {
  const int head = blockIdx.x;
  __shared__ float q[TOK][260];
  __shared__ float k[TOK][260];
  __shared__ float e[TOK][TOK];
  const int d = threadIdx.x;
#pragma unroll
  for (int n = 0; n < TOK; ++n) {
    const long base = (long)n * 12288 + (head * 256 + d) * 3;
    q[n][d] = qkv[base];
    k[n][d] = qkv[base + 1];
  }
  __syncthreads();
  for (int p = threadIdx.x; p < TOK * TOK; p += 256) {
    int i = p / TOK, j = p - i * TOK;
    float acc = 0.f;
#pragma unroll
    for (int kk = 0; kk < 256; kk += 4) {
      float4 a = *reinterpret_cast<const float4*>(&q[i][kk]);
      float4 bb = *reinterpret_cast<const float4*>(&k[j][kk]);
      acc = fmaf(a.x, bb.x, acc);
      acc = fmaf(a.y, bb.y, acc);
      acc = fmaf(a.z, bb.z, acc);
      acc = fmaf(a.w, bb.w, acc);
    }
    e[i][j] = acc;
  }
  __syncthreads();
  if (threadIdx.x < TOK) {
    const int i = threadIdx.x;
    float m = -1e30f;
    for (int j = 0; j < TOK; ++j) m = fmaxf(m, e[i][j]);
    float ssum = 0.f;
    float ex[TOK];
#pragma unroll
    for (int j = 0; j < TOK; ++j) {
      ex[j] = expf(e[i][j] - m);
      ssum += ex[j];
    }
    float inv = 1.f / (ssum * 64.f);  // softmax then /sqrt(4096)
#pragma unroll
    for (int j = 0; j < TOK; ++j) att[head * 625 + i * TOK + j] = ex[j] * inv;
  }
}

// ---------------- attention: att @ V -> o[25][4096]
__global__ __launch_bounds__(256) void k_attn_pv(const float* __restrict__ qkv,
                                                 const float* __restrict__ att,
                                                 float* __restrict__ o) {
  const int head = blockIdx.x;
  const int d = threadIdx.x;
  __shared__ float a[TOK * TOK];
  for (int i = threadIdx.x; i < TOK * TOK; i += 256) a[i] = att[head * 625 + i];
  __syncthreads();
  float acc[TOK];
#pragma unroll
  for (int i = 0; i < TOK; ++i) acc[i] = 0.f;
#pragma unroll
  for (int j = 0; j < TOK; ++j) {
    float vv = qkv[(long)j * 12288 + (head * 256 + d) * 3 + 2];
#pragma unroll
    for (int i = 0; i < TOK; ++i) acc[i] = fmaf(a[i * TOK + j], vv, acc[i]);
  }
#pragma unroll
  for (int i = 0; i < TOK; ++i) o[(long)i * 4096 + head * 256 + d] = acc[i];
}

extern "C" void kernel_launch(void* const* d_in, const int* in_sizes, int n_in,
                              void* d_out, int out_size, void* d_ws, size_t ws_size,
                              hipStream_t stream) {
  (void)in_sizes; (void)n_in; (void)out_size; (void)ws_size;
  const float* x      = (const float*)d_in[0];
  const float* pe_w   = (const float*)d_in[1];
  const float* pe_b   = (const float*)d_in[2];
  const float* pos    = (const float*)d_in[3];
  const float* ln_g   = (const float*)d_in[4];
  const float* ln_b   = (const float*)d_in[5];
  const float* qkv_w  = (const float*)d_in[6];
  const float* qkv_b  = (const float*)d_in[7];
  const float* proj_w = (const float*)d_in[8];
  const float* proj_b = (const float*)d_in[9];
  const float* ff1_w  = (const float*)d_in[10];
  const float* ff1_b  = (const float*)d_in[11];
  const float* ff2_w  = (const float*)d_in[12];
  const float* ff2_b  = (const float*)d_in[13];
  float* out = (float*)d_out;

  float* ws = (float*)d_ws;
  float* P    = ws;             // 102400
  float* T    = ws + 102400;    // 102400
  float* H    = ws + 204800;    // 102400
  float* QKV  = ws + 307200;    // 307200
  float* O    = ws + 614400;    // 102400
  float* G    = ws + 716800;    // 409600
  float* ATT  = ws + 1126400;   // 10000
  float* PART = ws + 1136400;   // max 32*25*4096 = 3.28M floats (13.1 MB)

  // 1. patch embedding: B = pe_w^T (WT=1), KC=256 -> S=16
  k_patchify<<<400, 256, 0, stream>>>(x, P);
  k_mfma<256, 1><<<dim3(64, 16), 256, 0, stream>>>(P, pe_w, PART, 4096, 4096);
  k_reduce<16, 0, 1><<<100, 256, 0, stream>>>(PART, pe_b, pos, T, 4096);
  k_ln<<<25, 256, 0, stream>>>(T, ln_g, ln_b, H);

  // 2. attention branch: qkv KC=512 -> S=8
  k_mfma<512, 0><<<dim3(192, 8), 256, 0, stream>>>(H, qkv_w, PART, 4096, 12288);
  k_reduce<8, 0, 0><<<300, 256, 0, stream>>>(PART, qkv_b, nullptr, QKV, 12288);
  k_attn_qk<<<16, 256, 0, stream>>>(QKV, ATT);
  k_attn_pv<<<16, 256, 0, stream>>>(QKV, ATT, O);
  k_mfma<256, 0><<<dim3(64, 16), 256, 0, stream>>>(O, proj_w, PART, 4096, 4096);
  k_reduce<16, 0, 1><<<100, 256, 0, stream>>>(PART, proj_b, T, T, 4096);
  k_ln<<<25, 256, 0, stream>>>(T, ln_g, ln_b, H);

  // 3. FFN branch: ff1 KC=512 -> S=8; ff2 KC=512 -> S=32
  k_mfma<512, 0><<<dim3(256, 8), 256, 0, stream>>>(H, ff1_w, PART, 4096, 16384);
  k_reduce<8, 1, 0><<<400, 256, 0, stream>>>(PART, ff1_b, nullptr, G, 16384);
  k_mfma<512, 0><<<dim3(64, 32), 256, 0, stream>>>(G, ff2_w, PART, 16384, 4096);
  k_reduce<32, 0, 1><<<100, 256, 0, stream>>>(PART, ff2_b, T, out, 4096);
}

// Round 7
// 252.193 us; speedup vs baseline: 2.5021x; 1.3062x over previous
//
#include <hip/hip_runtime.h>
#include <math.h>

#define TOK 25

typedef __attribute__((ext_vector_type(8))) short short8_t;   // 8 bf16
typedef __attribute__((ext_vector_type(4))) float f32x4_t;    // MFMA acc

// fp32 -> bf16 (round-to-nearest-even), bit pattern as short
__device__ __forceinline__ short bf16r(float f) {
  union { float f; unsigned u; } v;
  v.f = f;
  unsigned r = v.u + 0x7FFFu + ((v.u >> 16) & 1u);
  return (short)(r >> 16);
}
__device__ __forceinline__ unsigned packbf2(float lo, float hi) {
  return ((unsigned)(unsigned short)bf16r(hi) << 16) |
         (unsigned short)bf16r(lo);
}

// ---------------- patchify: x[1,256,20,20] -> P_bf[25][4096] bf16
__global__ __launch_bounds__(256) void k_patchify(const float* __restrict__ x,
                                                  unsigned short* __restrict__ P) {
  int idx = blockIdx.x * 256 + threadIdx.x;  // 0..102399
  int n = idx >> 12;
  int rem = idx & 4095;
  int c = rem >> 4;
  int kh = (rem >> 2) & 3;
  int kw = rem & 3;
  int py = n / 5, px = n - py * 5;
  P[idx] = (unsigned short)bf16r(x[c * 400 + (py * 4 + kh) * 20 + (px * 4 + kw)]);
}

// ---------------- MFMA GEMM: part[s][25][N] += A_bf[25][k-chunk] * W-chunk
// Block: 4 waves, 256 cols; wave owns 64 cols (4 groups of 16).
// A-tile staged in LDS (bf16, padded rows). No barrier in main loop.
// WT=0: W[K][N] (linear).  WT=1: W[N][K] (conv weight).
template <int KC, int WT>
__global__ __launch_bounds__(256) void k_mfma(
    const unsigned short* __restrict__ A, const float* __restrict__ W,
    float* __restrict__ part, int K, int N) {
  constexpr int LDA = KC + 8;  // bf16 elems per row; +16B pad -> 2-way banks
  __shared__ __align__(16) unsigned short As[TOK * LDA];
  const int tid = threadIdx.x;
  const int lane = tid & 63;
  const int lm = lane & 15;   // A row / B col within 16
  const int lg = lane >> 4;   // k-group (8 elems)
  const int wv = tid >> 6;
  const int s = blockIdx.y;
  const int k0 = s * KC;
  const int c0 = blockIdx.x * 256 + wv * 64;  // wave's first col
  // ---- stage A tile: 25 x KC bf16 (16B chunks)
  for (int i = tid; i < TOK * (KC / 8); i += 256) {
    int r = i / (KC / 8);
    int o = i - r * (KC / 8);
    uint4 v = *reinterpret_cast<const uint4*>(A + (long)r * K + k0 + o * 8);
    *reinterpret_cast<uint4*>(&As[r * LDA + o * 8]) = v;
  }
  __syncthreads();
  const int r1 = 16 + lm;
  const int r1c = (r1 < TOK) ? r1 : 0;  // clamped; tile-1 rows >=25 dropped
  f32x4_t acc[4][2];
#pragma unroll
  for (int g = 0; g < 4; ++g) {
    acc[g][0] = (f32x4_t){0.f, 0.f, 0.f, 0.f};
    acc[g][1] = (f32x4_t){0.f, 0.f, 0.f, 0.f};
  }
  for (int ks = 0; ks < KC; ks += 32) {
    const int kb = k0 + ks + lg * 8;
    // ---- B: 4 col-groups x 8 k-elements
    float bf[4][8];
    if (WT == 0) {
      const float* bp = W + (long)kb * N + c0 + lm;
#pragma unroll
      for (int j = 0; j < 8; ++j) {
        const float* bj = bp + (long)j * N;
#pragma unroll
        for (int g = 0; g < 4; ++g) bf[g][j] = bj[g * 16];
      }
    } else {
#pragma unroll
      for (int g = 0; g < 4; ++g) {
        const float* bp = W + (long)(c0 + g * 16 + lm) * K + kb;
        float4 b0 = *reinterpret_cast<const float4*>(bp);
        float4 b1 = *reinterpret_cast<const float4*>(bp + 4);
        bf[g][0] = b0.x; bf[g][1] = b0.y; bf[g][2] = b0.z; bf[g][3] = b0.w;
        bf[g][4] = b1.x; bf[g][5] = b1.y; bf[g][6] = b1.z; bf[g][7] = b1.w;
      }
    }
    // ---- A fragments from LDS (bf16, ready)
    short8_t av0 =
        *reinterpret_cast<const short8_t*>(&As[lm * LDA + ks + lg * 8]);
    short8_t av1 =
        *reinterpret_cast<const short8_t*>(&As[r1c * LDA + ks + lg * 8]);
#pragma unroll
    for (int g = 0; g < 4; ++g) {
      short8_t bv;
#pragma unroll
      for (int j = 0; j < 8; ++j) bv[j] = bf16r(bf[g][j]);
      acc[g][0] = __builtin_amdgcn_mfma_f32_16x16x32_bf16(av0, bv, acc[g][0], 0, 0, 0);
      acc[g][1] = __builtin_amdgcn_mfma_f32_16x16x32_bf16(av1, bv, acc[g][1], 0, 0, 0);
    }
  }
  // ---- store: C col=lane&15, row=lg*4+reg (+16 for tile 1)
  float* pp = part + ((long)s * TOK) * N + c0 + lm;
#pragma unroll
  for (int g = 0; g < 4; ++g) {
    float* pg = pp + g * 16;
#pragma unroll
    for (int r = 0; r < 4; ++r) {
      int row0 = lg * 4 + r;
      pg[(long)row0 * N] = acc[g][0][r];
      int row1 = 16 + lg * 4 + r;
      if (row1 < TOK) pg[(long)row1 * N] = acc[g][1][r];
    }
  }
}

// ---------------- reduce partials + bias (+gelu) (+residual); OBF: bf16 out
template <int S, int GELU, int RES, int OBF>
__global__ __launch_bounds__(256) void k_reduce(const float* __restrict__ part,
                                                const float* __restrict__ bias,
                                                const float* __restrict__ res,
                                                void* __restrict__ outv,
                                                int Nout) {
  long idx4 = (long)blockIdx.x * 256 + threadIdx.x;  // float4 index
  int c4 = (int)(idx4 % (Nout >> 2));
  const long stride4 = (long)TOK * (Nout >> 2);
  const float4* p4 = reinterpret_cast<const float4*>(part) + idx4;
  float4 v = {0.f, 0.f, 0.f, 0.f};
#pragma unroll
  for (int s = 0; s < S; ++s) {
    float4 t = p4[s * stride4];
    v.x += t.x; v.y += t.y; v.z += t.z; v.w += t.w;
  }
  float4 bb = reinterpret_cast<const float4*>(bias)[c4];
  v.x += bb.x; v.y += bb.y; v.z += bb.z; v.w += bb.w;
  if (GELU) {
    v.x = 0.5f * v.x * (1.f + erff(v.x * 0.70710678118654752f));
    v.y = 0.5f * v.y * (1.f + erff(v.y * 0.70710678118654752f));
    v.z = 0.5f * v.z * (1.f + erff(v.z * 0.70710678118654752f));
    v.w = 0.5f * v.w * (1.f + erff(v.w * 0.70710678118654752f));
  }
  if (RES) {
    float4 rr = reinterpret_cast<const float4*>(res)[idx4];
    v.x += rr.x; v.y += rr.y; v.z += rr.z; v.w += rr.w;
  }
  if (OBF) {
    uint2 o;
    o.x = packbf2(v.x, v.y);
    o.y = packbf2(v.z, v.w);
    reinterpret_cast<uint2*>(outv)[idx4] = o;
  } else {
    reinterpret_cast<float4*>(outv)[idx4] = v;
  }
}

// ---------------- LayerNorm over 4096, one block per token -> bf16 out
__global__ __launch_bounds__(256) void k_ln(const float* __restrict__ t,
                                            const float* __restrict__ g,
                                            const float* __restrict__ b,
                                            unsigned short* __restrict__ h) {
  const int n = blockIdx.x;
  const float4* row = reinterpret_cast<const float4*>(t + n * 4096);
  float s = 0.f, s2 = 0.f;
  float4 vbuf[4];
#pragma unroll
  for (int it = 0; it < 4; ++it) {
    float4 v = row[threadIdx.x + it * 256];
    vbuf[it] = v;
    s += v.x + v.y + v.z + v.w;
    s2 += v.x * v.x + v.y * v.y + v.z * v.z + v.w * v.w;
  }
#pragma unroll
  for (int off = 32; off >= 1; off >>= 1) {
    s += __shfl_down(s, off);
    s2 += __shfl_down(s2, off);
  }
  __shared__ float red[8];
  if ((threadIdx.x & 63) == 0) {
    red[threadIdx.x >> 6] = s;
    red[4 + (threadIdx.x >> 6)] = s2;
  }
  __syncthreads();
  float st = red[0] + red[1] + red[2] + red[3];
  float s2t = red[4] + red[5] + red[6] + red[7];
  float mean = st * (1.f / 4096.f);
  float var = s2t * (1.f / 4096.f) - mean * mean;
  float rstd = rsqrtf(var + 1e-5f);
  const float4* g4 = reinterpret_cast<const float4*>(g);
  const float4* b4 = reinterpret_cast<const float4*>(b);
  uint2* h2 = reinterpret_cast<uint2*>(h) + (long)n * 1024;
#pragma unroll
  for (int it = 0; it < 4; ++it) {
    int i = threadIdx.x + it * 256;
    float4 v = vbuf[it];
    float4 gg = g4[i];
    float4 bb = b4[i];
    float4 o;
    o.x = (v.x - mean) * rstd * gg.x + bb.x;
    o.y = (v.y - mean) * rstd * gg.y + bb.y;
    o.z = (v.z - mean) * rstd * gg.z + bb.z;
    o.w = (v.w - mean) * rstd * gg.w + bb.w;
    uint2 pk;
    pk.x = packbf2(o.x, o.y);
    pk.y = packbf2(o.z, o.w);
    h2[i] = pk;
  }
}

// ---------------- attention: QK^T + softmax/64 -> att[16][25][25]
__global__ __launch_bounds__(256) void k_attn_qk(const float* __restrict__ qkv,
                                                 float* __restrict__ att) {
  const int head = blockIdx.x;
  __shared__ float q[TOK][260];
  __shared__ float k[TOK][260];
  __shared__ float e[TOK][TOK];
  const int d = threadIdx.x;
#pragma unroll
  for (int n = 0; n < TOK; ++n) {
    const long base = (long)n * 12288 + (head * 256 + d) * 3;
    q[n][d] = qkv[base];
    k[n][d] = qkv[base + 1];
  }
  __syncthreads();
  for (int p = threadIdx.x; p < TOK * TOK; p += 256) {
    int i = p / TOK, j = p - i * TOK;
    float acc = 0.f;
#pragma unroll
    for (int kk = 0; kk < 256; kk += 4) {
      float4 a = *reinterpret_cast<const float4*>(&q[i][kk]);
      float4 bb = *reinterpret_cast<const float4*>(&k[j][kk]);
      acc = fmaf(a.x, bb.x, acc);
      acc = fmaf(a.y, bb.y, acc);
      acc = fmaf(a.z, bb.z, acc);
      acc = fmaf(a.w, bb.w, acc);
    }
    e[i][j] = acc;
  }
  __syncthreads();
  if (threadIdx.x < TOK) {
    const int i = threadIdx.x;
    float m = -1e30f;
    for (int j = 0; j < TOK; ++j) m = fmaxf(m, e[i][j]);
    float ssum = 0.f;
    float ex[TOK];
#pragma unroll
    for (int j = 0; j < TOK; ++j) {
      ex[j] = expf(e[i][j] - m);
      ssum += ex[j];
    }
    float inv = 1.f / (ssum * 64.f);  // softmax then /sqrt(4096)
#pragma unroll
    for (int j = 0; j < TOK; ++j) att[head * 625 + i * TOK + j] = ex[j] * inv;
  }
}

// ---------------- attention: att @ V -> O_bf[25][4096] bf16
__global__ __launch_bounds__(256) void k_attn_pv(const float* __restrict__ qkv,
                                                 const float* __restrict__ att,
                                                 unsigned short* __restrict__ o) {
  const int head = blockIdx.x;
  const int d = threadIdx.x;
  __shared__ float a[TOK * TOK];
  for (int i = threadIdx.x; i < TOK * TOK; i += 256) a[i] = att[head * 625 + i];
  __syncthreads();
  float acc[TOK];
#pragma unroll
  for (int i = 0; i < TOK; ++i) acc[i] = 0.f;
#pragma unroll
  for (int j = 0; j < TOK; ++j) {
    float vv = qkv[(long)j * 12288 + (head * 256 + d) * 3 + 2];
#pragma unroll
    for (int i = 0; i < TOK; ++i) acc[i] = fmaf(a[i * TOK + j], vv, acc[i]);
  }
#pragma unroll
  for (int i = 0; i < TOK; ++i)
    o[(long)i * 4096 + head * 256 + d] = (unsigned short)bf16r(acc[i]);
}

extern "C" void kernel_launch(void* const* d_in, const int* in_sizes, int n_in,
                              void* d_out, int out_size, void* d_ws, size_t ws_size,
                              hipStream_t stream) {
  (void)in_sizes; (void)n_in; (void)out_size; (void)ws_size;
  const float* x      = (const float*)d_in[0];
  const float* pe_w   = (const float*)d_in[1];
  const float* pe_b   = (const float*)d_in[2];
  const float* pos    = (const float*)d_in[3];
  const float* ln_g   = (const float*)d_in[4];
  const float* ln_b   = (const float*)d_in[5];
  const float* qkv_w  = (const float*)d_in[6];
  const float* qkv_b  = (const float*)d_in[7];
  const float* proj_w = (const float*)d_in[8];
  const float* proj_b = (const float*)d_in[9];
  const float* ff1_w  = (const float*)d_in[10];
  const float* ff1_b  = (const float*)d_in[11];
  const float* ff2_w  = (const float*)d_in[12];
  const float* ff2_b  = (const float*)d_in[13];
  float* out = (float*)d_out;

  float* ws = (float*)d_ws;
  unsigned short* P_bf = (unsigned short*)ws;                 // 102400 bf16
  float* T    = ws + 102400;    // 102400 f32
  unsigned short* H_bf = (unsigned short*)(ws + 204800);      // 102400 bf16
  float* QKV  = ws + 307200;    // 307200 f32
  unsigned short* O_bf = (unsigned short*)(ws + 614400);      // 102400 bf16
  unsigned short* G_bf = (unsigned short*)(ws + 716800);      // 409600 bf16
  float* ATT  = ws + 1126400;   // 10000
  float* PART = ws + 1136400;   // max 16*25*16384 f32 = 26.2 MB

  // 1. patch embedding: WT=1, KC=128 -> S=32, grid(16,32)=512 blocks
  k_patchify<<<400, 256, 0, stream>>>(x, P_bf);
  k_mfma<128, 1><<<dim3(16, 32), 256, 0, stream>>>(P_bf, pe_w, PART, 4096, 4096);
  k_reduce<32, 0, 1, 0><<<100, 256, 0, stream>>>(PART, pe_b, pos, T, 4096);
  k_ln<<<25, 256, 0, stream>>>(T, ln_g, ln_b, H_bf);

  // 2. attention branch: qkv KC=256 -> S=16, grid(48,16)=768
  k_mfma<256, 0><<<dim3(48, 16), 256, 0, stream>>>(H_bf, qkv_w, PART, 4096, 12288);
  k_reduce<16, 0, 0, 0><<<300, 256, 0, stream>>>(PART, qkv_b, nullptr, QKV, 12288);
  k_attn_qk<<<16, 256, 0, stream>>>(QKV, ATT);
  k_attn_pv<<<16, 256, 0, stream>>>(QKV, ATT, O_bf);
  // proj KC=128 -> S=32, grid(16,32)=512
  k_mfma<128, 0><<<dim3(16, 32), 256, 0, stream>>>(O_bf, proj_w, PART, 4096, 4096);
  k_reduce<32, 0, 1, 0><<<100, 256, 0, stream>>>(PART, proj_b, T, T, 4096);
  k_ln<<<25, 256, 0, stream>>>(T, ln_g, ln_b, H_bf);

  // 3. FFN: ff1 KC=256 -> S=16, grid(64,16)=1024; bf16 out
  k_mfma<256, 0><<<dim3(64, 16), 256, 0, stream>>>(H_bf, ff1_w, PART, 4096, 16384);
  k_reduce<16, 1, 0, 1><<<400, 256, 0, stream>>>(PART, ff1_b, nullptr, G_bf, 16384);
  // ff2 KC=512 -> S=32, grid(16,32)=512
  k_mfma<512, 0><<<dim3(16, 32), 256, 0, stream>>>(G_bf, ff2_w, PART, 16384, 4096);
  k_reduce<32, 0, 1, 0><<<100, 256, 0, stream>>>(PART, ff2_b, T, out, 4096);
}

// Round 8
// 243.280 us; speedup vs baseline: 2.5937x; 1.0366x over previous
//
#include <hip/hip_runtime.h>
#include <math.h>

#define TOK 25

typedef __attribute__((ext_vector_type(8))) short short8_t;   // 8 bf16 (MFMA frag)
typedef __attribute__((ext_vector_type(4))) float f32x4_t;    // MFMA acc
typedef __attribute__((ext_vector_type(8))) float floatx8;
typedef __attribute__((ext_vector_type(4))) float floatx4;
typedef __attribute__((ext_vector_type(8))) __bf16 bf16x8_t;
typedef __attribute__((ext_vector_type(4))) __bf16 bf16x4_t;

// f32x8 -> bf16x8 via v_cvt_pk_bf16_f32 (compiler-lowered), as MFMA short8 frag
__device__ __forceinline__ short8_t cvt8(floatx8 f) {
  return __builtin_bit_cast(short8_t, __builtin_convertvector(f, bf16x8_t));
}
__device__ __forceinline__ uint2 cvt4pack(float4 v) {
  floatx4 f = {v.x, v.y, v.z, v.w};
  return __builtin_bit_cast(uint2, __builtin_convertvector(f, bf16x4_t));
}
__device__ __forceinline__ unsigned short bf1(float f) {
  return __builtin_bit_cast(unsigned short, (__bf16)f);
}

// ---------------- MFMA GEMM: part[s][25][N] = A_bf[25][k-chunk] * W-chunk
// Block: 4 waves, 256 cols; wave owns 64 cols (4 groups of 16).
// A-tile staged in LDS (bf16, padded). No barrier in main loop.
// WT=0: W[K][N] (linear layers).  WT=1: W[N][K] (transposed weight).
template <int KC, int WT>
__global__ __launch_bounds__(256) void k_mfma(
    const unsigned short* __restrict__ A, const float* __restrict__ W,
    float* __restrict__ part, int K, int N) {
  constexpr int LDA = KC + 8;  // bf16 elems/row; +16B pad
  __shared__ __align__(16) unsigned short As[TOK * LDA];
  const int tid = threadIdx.x;
  const int lane = tid & 63;
  const int lm = lane & 15;   // A row / B col within 16
  const int lg = lane >> 4;   // k-group (8 elems)
  const int wv = tid >> 6;
  const int s = blockIdx.y;
  const int k0 = s * KC;
  const int c0 = blockIdx.x * 256 + wv * 64;  // wave's first col
  // ---- stage A tile: 25 x KC bf16
  for (int i = tid; i < TOK * (KC / 8); i += 256) {
    int r = i / (KC / 8);
    int o = i - r * (KC / 8);
    uint4 v = *reinterpret_cast<const uint4*>(A + (long)r * K + k0 + o * 8);
    *reinterpret_cast<uint4*>(&As[r * LDA + o * 8]) = v;
  }
  __syncthreads();
  const int r1 = 16 + lm;
  const int r1c = (r1 < TOK) ? r1 : 0;  // clamped; tile-1 rows >=25 dropped
  f32x4_t acc[4][2];
#pragma unroll
  for (int g = 0; g < 4; ++g) {
    acc[g][0] = (f32x4_t){0.f, 0.f, 0.f, 0.f};
    acc[g][1] = (f32x4_t){0.f, 0.f, 0.f, 0.f};
  }
  for (int ks = 0; ks < KC; ks += 32) {
    const int kb = k0 + ks + lg * 8;
    floatx8 bfv[4];
    if (WT == 0) {
      const float* bp = W + (long)kb * N + c0 + lm;
#pragma unroll
      for (int j = 0; j < 8; ++j) {
        const float* bj = bp + (long)j * N;
#pragma unroll
        for (int g = 0; g < 4; ++g) bfv[g][j] = bj[g * 16];
      }
    } else {
#pragma unroll
      for (int g = 0; g < 4; ++g) {
        const float* bp = W + (long)(c0 + g * 16 + lm) * K + kb;
        float4 b0 = *reinterpret_cast<const float4*>(bp);
        float4 b1 = *reinterpret_cast<const float4*>(bp + 4);
        bfv[g] = (floatx8){b0.x, b0.y, b0.z, b0.w, b1.x, b1.y, b1.z, b1.w};
      }
    }
    short8_t av0 =
        *reinterpret_cast<const short8_t*>(&As[lm * LDA + ks + lg * 8]);
    short8_t av1 =
        *reinterpret_cast<const short8_t*>(&As[r1c * LDA + ks + lg * 8]);
#pragma unroll
    for (int g = 0; g < 4; ++g) {
      short8_t bv = cvt8(bfv[g]);
      acc[g][0] = __builtin_amdgcn_mfma_f32_16x16x32_bf16(av0, bv, acc[g][0], 0, 0, 0);
      acc[g][1] = __builtin_amdgcn_mfma_f32_16x16x32_bf16(av1, bv, acc[g][1], 0, 0, 0);
    }
  }
  float* pp = part + ((long)s * TOK) * N + c0 + lm;
#pragma unroll
  for (int g = 0; g < 4; ++g) {
    float* pg = pp + g * 16;
#pragma unroll
    for (int r = 0; r < 4; ++r) {
      int row0 = lg * 4 + r;
      pg[(long)row0 * N] = acc[g][0][r];
      int row1 = 16 + lg * 4 + r;
      if (row1 < TOK) pg[(long)row1 * N] = acc[g][1][r];
    }
  }
}

// ---------------- patch-embed MFMA GEMM: A staged by gathering x directly.
// A[n][k] = x[c*400 + (py*4+kh)*20 + px*4+kw], k = c*16+kh*4+kw; W=pe_w[N][K].
template <int KC>
__global__ __launch_bounds__(256) void k_mfma_pe(
    const float* __restrict__ x, const float* __restrict__ W,
    float* __restrict__ part, int K, int N) {
  constexpr int LDA = KC + 8;
  __shared__ __align__(16) unsigned short As[TOK * LDA];
  const int tid = threadIdx.x;
  const int lane = tid & 63;
  const int lm = lane & 15;
  const int lg = lane >> 4;
  const int wv = tid >> 6;
  const int s = blockIdx.y;
  const int k0 = s * KC;
  const int c0 = blockIdx.x * 256 + wv * 64;
  // ---- stage A tile by gather+convert (8 k = 2 float4 from x)
  for (int i = tid; i < TOK * (KC / 8); i += 256) {
    int r = i / (KC / 8);
    int o = i - r * (KC / 8);
    int kb = k0 + o * 8;
    int c = kb >> 4;
    int kh0 = (kb >> 2) & 3;  // 0 or 2 (kb % 8 == 0)
    int py = r / 5, px = r - py * 5;
    const float* xp = x + c * 400 + (py * 4 + kh0) * 20 + px * 4;
    float4 lo = *reinterpret_cast<const float4*>(xp);
    float4 hi = *reinterpret_cast<const float4*>(xp + 20);
    floatx8 f = {lo.x, lo.y, lo.z, lo.w, hi.x, hi.y, hi.z, hi.w};
    short8_t v = cvt8(f);
    *reinterpret_cast<short8_t*>(&As[r * LDA + o * 8]) = v;
  }
  __syncthreads();
  const int r1 = 16 + lm;
  const int r1c = (r1 < TOK) ? r1 : 0;
  f32x4_t acc[4][2];
#pragma unroll
  for (int g = 0; g < 4; ++g) {
    acc[g][0] = (f32x4_t){0.f, 0.f, 0.f, 0.f};
    acc[g][1] = (f32x4_t){0.f, 0.f, 0.f, 0.f};
  }
  for (int ks = 0; ks < KC; ks += 32) {
    const int kb = k0 + ks + lg * 8;
    floatx8 bfv[4];
#pragma unroll
    for (int g = 0; g < 4; ++g) {
      const float* bp = W + (long)(c0 + g * 16 + lm) * K + kb;
      float4 b0 = *reinterpret_cast<const float4*>(bp);
      float4 b1 = *reinterpret_cast<const float4*>(bp + 4);
      bfv[g] = (floatx8){b0.x, b0.y, b0.z, b0.w, b1.x, b1.y, b1.z, b1.w};
    }
    short8_t av0 =
        *reinterpret_cast<const short8_t*>(&As[lm * LDA + ks + lg * 8]);
    short8_t av1 =
        *reinterpret_cast<const short8_t*>(&As[r1c * LDA + ks + lg * 8]);
#pragma unroll
    for (int g = 0; g < 4; ++g) {
      short8_t bv = cvt8(bfv[g]);
      acc[g][0] = __builtin_amdgcn_mfma_f32_16x16x32_bf16(av0, bv, acc[g][0], 0, 0, 0);
      acc[g][1] = __builtin_amdgcn_mfma_f32_16x16x32_bf16(av1, bv, acc[g][1], 0, 0, 0);
    }
  }
  float* pp = part + ((long)s * TOK) * N + c0 + lm;
#pragma unroll
  for (int g = 0; g < 4; ++g) {
    float* pg = pp + g * 16;
#pragma unroll
    for (int r = 0; r < 4; ++r) {
      int row0 = lg * 4 + r;
      pg[(long)row0 * N] = acc[g][0][r];
      int row1 = 16 + lg * 4 + r;
      if (row1 < TOK) pg[(long)row1 * N] = acc[g][1][r];
    }
  }
}

// ---------------- reduce partials + bias (+gelu) (+residual); OBF: bf16 out
template <int S, int GELU, int RES, int OBF>
__global__ __launch_bounds__(256) void k_reduce(const float* __restrict__ part,
                                                const float* __restrict__ bias,
                                                const float* __restrict__ res,
                                                void* __restrict__ outv,
                                                int Nout) {
  long idx4 = (long)blockIdx.x * 256 + threadIdx.x;  // float4 index
  int c4 = (int)(idx4 % (Nout >> 2));
  const long stride4 = (long)TOK * (Nout >> 2);
  const float4* p4 = reinterpret_cast<const float4*>(part) + idx4;
  float4 v = {0.f, 0.f, 0.f, 0.f};
#pragma unroll
  for (int s = 0; s < S; ++s) {
    float4 t = p4[s * stride4];
    v.x += t.x; v.y += t.y; v.z += t.z; v.w += t.w;
  }
  float4 bb = reinterpret_cast<const float4*>(bias)[c4];
  v.x += bb.x; v.y += bb.y; v.z += bb.z; v.w += bb.w;
  if (GELU) {
    v.x = 0.5f * v.x * (1.f + erff(v.x * 0.70710678118654752f));
    v.y = 0.5f * v.y * (1.f + erff(v.y * 0.70710678118654752f));
    v.z = 0.5f * v.z * (1.f + erff(v.z * 0.70710678118654752f));
    v.w = 0.5f * v.w * (1.f + erff(v.w * 0.70710678118654752f));
  }
  if (RES) {
    float4 rr = reinterpret_cast<const float4*>(res)[idx4];
    v.x += rr.x; v.y += rr.y; v.z += rr.z; v.w += rr.w;
  }
  if (OBF) {
    reinterpret_cast<uint2*>(outv)[idx4] = cvt4pack(v);
  } else {
    reinterpret_cast<float4*>(outv)[idx4] = v;
  }
}

// ---------------- LayerNorm over 4096, one block per token -> bf16 out
__global__ __launch_bounds__(256) void k_ln(const float* __restrict__ t,
                                            const float* __restrict__ g,
                                            const float* __restrict__ b,
                                            unsigned short* __restrict__ h) {
  const int n = blockIdx.x;
  const float4* row = reinterpret_cast<const float4*>(t + n * 4096);
  float s = 0.f, s2 = 0.f;
  float4 vbuf[4];
#pragma unroll
  for (int it = 0; it < 4; ++it) {
    float4 v = row[threadIdx.x + it * 256];
    vbuf[it] = v;
    s += v.x + v.y + v.z + v.w;
    s2 += v.x * v.x + v.y * v.y + v.z * v.z + v.w * v.w;
  }
#pragma unroll
  for (int off = 32; off >= 1; off >>= 1) {
    s += __shfl_down(s, off);
    s2 += __shfl_down(s2, off);
  }
  __shared__ float red[8];
  if ((threadIdx.x & 63) == 0) {
    red[threadIdx.x >> 6] = s;
    red[4 + (threadIdx.x >> 6)] = s2;
  }
  __syncthreads();
  float st = red[0] + red[1] + red[2] + red[3];
  float s2t = red[4] + red[5] + red[6] + red[7];
  float mean = st * (1.f / 4096.f);
  float var = s2t * (1.f / 4096.f) - mean * mean;
  float rstd = rsqrtf(var + 1e-5f);
  const float4* g4 = reinterpret_cast<const float4*>(g);
  const float4* b4 = reinterpret_cast<const float4*>(b);
  uint2* h2 = reinterpret_cast<uint2*>(h) + (long)n * 1024;
#pragma unroll
  for (int it = 0; it < 4; ++it) {
    int i = threadIdx.x + it * 256;
    float4 v = vbuf[it];
    float4 gg = g4[i];
    float4 bb = b4[i];
    float4 o;
    o.x = (v.x - mean) * rstd * gg.x + bb.x;
    o.y = (v.y - mean) * rstd * gg.y + bb.y;
    o.z = (v.z - mean) * rstd * gg.z + bb.z;
    o.w = (v.w - mean) * rstd * gg.w + bb.w;
    h2[i] = cvt4pack(o);
  }
}

// ---------------- fused attention: QK^T + softmax/64 + PV -> O_bf[25][4096]
__global__ __launch_bounds__(256) void k_attn(const float* __restrict__ qkv,
                                              unsigned short* __restrict__ o) {
  const int head = blockIdx.x;
  __shared__ float q[TOK][260];
  __shared__ float kk[TOK][260];
  __shared__ float att[TOK][TOK];
  const int d = threadIdx.x;
#pragma unroll
  for (int n = 0; n < TOK; ++n) {
    const long base = (long)n * 12288 + (head * 256 + d) * 3;
    q[n][d] = qkv[base];
    kk[n][d] = qkv[base + 1];
  }
  __syncthreads();
  for (int p = threadIdx.x; p < TOK * TOK; p += 256) {
    int i = p / TOK, j = p - i * TOK;
    float acc = 0.f;
#pragma unroll
    for (int c = 0; c < 256; c += 4) {
      float4 a = *reinterpret_cast<const float4*>(&q[i][c]);
      float4 bb = *reinterpret_cast<const float4*>(&kk[j][c]);
      acc = fmaf(a.x, bb.x, acc);
      acc = fmaf(a.y, bb.y, acc);
      acc = fmaf(a.z, bb.z, acc);
      acc = fmaf(a.w, bb.w, acc);
    }
    att[i][j] = acc;
  }
  __syncthreads();
  if (threadIdx.x < TOK) {
    const int i = threadIdx.x;
    float m = -1e30f;
    for (int j = 0; j < TOK; ++j) m = fmaxf(m, att[i][j]);
    float ssum = 0.f;
    float ex[TOK];
#pragma unroll
    for (int j = 0; j < TOK; ++j) {
      ex[j] = expf(att[i][j] - m);
      ssum += ex[j];
    }
    float inv = 1.f / (ssum * 64.f);  // softmax then /sqrt(4096)
#pragma unroll
    for (int j = 0; j < TOK; ++j) att[i][j] = ex[j] * inv;
  }
  __syncthreads();
  float acc[TOK];
#pragma unroll
  for (int i = 0; i < TOK; ++i) acc[i] = 0.f;
#pragma unroll
  for (int j = 0; j < TOK; ++j) {
    float vv = qkv[(long)j * 12288 + (head * 256 + d) * 3 + 2];
#pragma unroll
    for (int i = 0; i < TOK; ++i) acc[i] = fmaf(att[i][j], vv, acc[i]);
  }
#pragma unroll
  for (int i = 0; i < TOK; ++i)
    o[(long)i * 4096 + head * 256 + d] = bf1(acc[i]);
}

extern "C" void kernel_launch(void* const* d_in, const int* in_sizes, int n_in,
                              void* d_out, int out_size, void* d_ws, size_t ws_size,
                              hipStream_t stream) {
  (void)in_sizes; (void)n_in; (void)out_size; (void)ws_size;
  const float* x      = (const float*)d_in[0];
  const float* pe_w   = (const float*)d_in[1];
  const float* pe_b   = (const float*)d_in[2];
  const float* pos    = (const float*)d_in[3];
  const float* ln_g   = (const float*)d_in[4];
  const float* ln_b   = (const float*)d_in[5];
  const float* qkv_w  = (const float*)d_in[6];
  const float* qkv_b  = (const float*)d_in[7];
  const float* proj_w = (const float*)d_in[8];
  const float* proj_b = (const float*)d_in[9];
  const float* ff1_w  = (const float*)d_in[10];
  const float* ff1_b  = (const float*)d_in[11];
  const float* ff2_w  = (const float*)d_in[12];
  const float* ff2_b  = (const float*)d_in[13];
  float* out = (float*)d_out;

  float* ws = (float*)d_ws;
  float* T    = ws + 102400;    // 102400 f32
  unsigned short* H_bf = (unsigned short*)(ws + 204800);      // 102400 bf16
  float* QKV  = ws + 307200;    // 307200 f32
  unsigned short* O_bf = (unsigned short*)(ws + 614400);      // 102400 bf16
  unsigned short* G_bf = (unsigned short*)(ws + 716800);      // 409600 bf16
  float* PART = ws + 1136400;   // max 16*25*16384 f32 = 26.2 MB

  // 1. patch embedding (patchify fused into A-stage): KC=128 -> S=32
  k_mfma_pe<128><<<dim3(16, 32), 256, 0, stream>>>(x, pe_w, PART, 4096, 4096);
  k_reduce<32, 0, 1, 0><<<100, 256, 0, stream>>>(PART, pe_b, pos, T, 4096);
  k_ln<<<25, 256, 0, stream>>>(T, ln_g, ln_b, H_bf);

  // 2. attention branch: qkv KC=256 -> S=16, grid(48,16)=768
  k_mfma<256, 0><<<dim3(48, 16), 256, 0, stream>>>(H_bf, qkv_w, PART, 4096, 12288);
  k_reduce<16, 0, 0, 0><<<300, 256, 0, stream>>>(PART, qkv_b, nullptr, QKV, 12288);
  k_attn<<<16, 256, 0, stream>>>(QKV, O_bf);
  // proj KC=128 -> S=32, grid(16,32)=512
  k_mfma<128, 0><<<dim3(16, 32), 256, 0, stream>>>(O_bf, proj_w, PART, 4096, 4096);
  k_reduce<32, 0, 1, 0><<<100, 256, 0, stream>>>(PART, proj_b, T, T, 4096);
  k_ln<<<25, 256, 0, stream>>>(T, ln_g, ln_b, H_bf);

  // 3. FFN: ff1 KC=256 -> S=16, grid(64,16)=1024; bf16 out
  k_mfma<256, 0><<<dim3(64, 16), 256, 0, stream>>>(H_bf, ff1_w, PART, 4096, 16384);
  k_reduce<16, 1, 0, 1><<<400, 256, 0, stream>>>(PART, ff1_b, nullptr, G_bf, 16384);
  // ff2 KC=512 -> S=32, grid(16,32)=512
  k_mfma<512, 0><<<dim3(16, 32), 256, 0, stream>>>(G_bf, ff2_w, PART, 16384, 4096);
  k_reduce<32, 0, 1, 0><<<100, 256, 0, stream>>>(PART, ff2_b, T, out, 4096);
}